// Round 16
// baseline (483.547 us; speedup 1.0000x reference)
//
#include <hip/hip_runtime.h>
#include <math.h>

#define N_NODES 100000
#define N_EDGES 1600000
#define N_QUERY 200000
#define NODE_IN 32
#define EDGE_IN 8
#define H 64
#define LAYERS 3
#define LN_EPS 1e-5f
#define BN_EPS 1e-5f
#define NBLK 391
#define NBUK 391
#define ACHUNK 4096
#define CAPB 6144

typedef __attribute__((ext_vector_type(8))) short short8b;
typedef __attribute__((ext_vector_type(4))) float f32x4;

__device__ __forceinline__ float gelu_f(float x){
    return 0.5f * x * (1.0f + erff(x * 0.70710678118654752440f));
}
__device__ __forceinline__ ushort f2bf(float x){  // RNE f32->bf16
    unsigned u = __float_as_uint(x);
    unsigned r = (u + 0x7FFFu + ((u >> 16) & 1u)) >> 16;
    return (ushort)r;
}
__device__ __forceinline__ float bf2f(ushort x){
    return __uint_as_float(((unsigned)x) << 16);
}

// ---------------- CSR build (bucketed) ----------------
__global__ __launch_bounds__(256) void k_count(const int* __restrict__ ei, int* __restrict__ c){
    int i = blockIdx.x * 256 + threadIdx.x;
    if (i < N_EDGES) atomicAdd(&c[ei[N_EDGES + i]], 1);
}
__global__ __launch_bounds__(256) void k_scanA(const int* __restrict__ cnt, int* __restrict__ bsum){
    int i = blockIdx.x * 256 + threadIdx.x;
    int v = (i < N_NODES) ? cnt[i] : 0;
    #pragma unroll
    for (int off = 32; off; off >>= 1) v += __shfl_xor(v, off, 64);
    __shared__ int ws[4];
    if ((threadIdx.x & 63) == 0) ws[threadIdx.x >> 6] = v;
    __syncthreads();
    if (threadIdx.x == 0) bsum[blockIdx.x] = ws[0] + ws[1] + ws[2] + ws[3];
}
__global__ __launch_bounds__(512) void k_scanB(int* __restrict__ bsum){
    __shared__ int s[512];
    int t = threadIdx.x;
    int v = (t < NBLK) ? bsum[t] : 0;
    s[t] = v; __syncthreads();
    for (int off = 1; off < 512; off <<= 1){
        int u = (t >= off) ? s[t - off] : 0;
        __syncthreads();
        s[t] += u;
        __syncthreads();
    }
    if (t < NBLK) bsum[t] = s[t] - v;
}
__global__ __launch_bounds__(256) void k_scanC(const int* __restrict__ cnt, const int* __restrict__ bsum,
                                               int* __restrict__ rs, int* __restrict__ bcur){
    __shared__ int s[256];
    int t = threadIdx.x;
    int i = blockIdx.x * 256 + t;
    int v = (i < N_NODES) ? cnt[i] : 0;
    s[t] = v; __syncthreads();
    for (int off = 1; off < 256; off <<= 1){
        int u = (t >= off) ? s[t - off] : 0;
        __syncthreads();
        s[t] += u;
        __syncthreads();
    }
    int pref = bsum[blockIdx.x] + s[t] - v;
    if (i < N_NODES) rs[i] = pref;
    if (i == N_NODES - 1) rs[N_NODES] = pref + v;
    if (t == 0) bcur[blockIdx.x] = bsum[blockIdx.x];
}
__global__ __launch_bounds__(1024) void k_bucketA(const int* __restrict__ ei, int* __restrict__ bcur,
                                                  int* __restrict__ bucketed){
    __shared__ int hist[NBUK], pref[NBUK], curl[NBUK], gbase[NBUK];
    __shared__ int scan[512];
    __shared__ int stageP[ACHUNK];
    __shared__ ushort stageB[ACHUNK];
    int tid = threadIdx.x;
    int e0 = blockIdx.x * ACHUNK;
    int cnt = N_EDGES - e0;
    if (cnt > ACHUNK) cnt = ACHUNK;
    for (int b = tid; b < NBUK; b += 1024) hist[b] = 0;
    __syncthreads();
    int myd[4], mys[4];
    #pragma unroll
    for (int i = 0; i < 4; ++i){
        int idx = tid + i * 1024;
        if (idx < cnt){
            int e = e0 + idx;
            mys[i] = ei[e];
            myd[i] = ei[N_EDGES + e];
            atomicAdd(&hist[myd[i] >> 8], 1);
        } else myd[i] = -1;
    }
    __syncthreads();
    int v = (tid < NBUK) ? hist[tid] : 0;
    if (tid < 512) scan[tid] = v;
    __syncthreads();
    for (int off = 1; off < 512; off <<= 1){
        int u = 0;
        if (tid < 512 && tid >= off) u = scan[tid - off];
        __syncthreads();
        if (tid < 512) scan[tid] += u;
        __syncthreads();
    }
    if (tid < NBUK){
        int ex = scan[tid] - v;
        pref[tid] = ex;
        curl[tid] = ex;
        if (v > 0) gbase[tid] = atomicAdd(&bcur[tid], v);
    }
    __syncthreads();
    #pragma unroll
    for (int i = 0; i < 4; ++i){
        if (myd[i] >= 0){
            int b = myd[i] >> 8;
            int p = atomicAdd(&curl[b], 1);
            stageP[p] = (mys[i] << 8) | (myd[i] & 255);
            stageB[p] = (ushort)b;
        }
    }
    __syncthreads();
    for (int p = tid; p < cnt; p += 1024){
        int b = stageB[p];
        bucketed[gbase[b] + (p - pref[b])] = stageP[p];
    }
}
__global__ __launch_bounds__(1024) void k_fillB(const int* __restrict__ rs, int* __restrict__ csr){
    __shared__ int packed[CAPB];
    __shared__ int sorted[CAPB];
    __shared__ int hist[256], cur[256];
    __shared__ int scan[256];
    int tid = threadIdx.x;
    int node0 = blockIdx.x * 256;
    int node1 = node0 + 256; if (node1 > N_NODES) node1 = N_NODES;
    int r0 = rs[node0], r1 = rs[node1];
    int L = r1 - r0;
    if (tid < 256) hist[tid] = 0;
    __syncthreads();
    for (int i = tid; i < L; i += 1024){
        int pk = csr[r0 + i];
        packed[i] = pk;
        atomicAdd(&hist[pk & 255], 1);
    }
    __syncthreads();
    int v = (tid < 256) ? hist[tid] : 0;
    if (tid < 256) scan[tid] = v;
    __syncthreads();
    for (int off = 1; off < 256; off <<= 1){
        int u = 0;
        if (tid < 256 && tid >= off) u = scan[tid - off];
        __syncthreads();
        if (tid < 256) scan[tid] += u;
        __syncthreads();
    }
    if (tid < 256) cur[tid] = scan[tid] - v;
    __syncthreads();
    for (int i = tid; i < L; i += 1024){
        int pk = packed[i];
        int p = atomicAdd(&cur[pk & 255], 1);
        sorted[p] = pk >> 8;
    }
    __syncthreads();
    for (int i = tid; i < L; i += 1024) csr[r0 + i] = sorted[i];
}

// ---------------- node encoder (f32 + flat bf16 mirror) ----------------
__global__ __launch_bounds__(256) void k_enc(const float* __restrict__ x, const float* __restrict__ Wenc,
                                             const float* __restrict__ benc, float* __restrict__ h,
                                             ushort* __restrict__ hbf){
    __shared__ __align__(16) float sW[NODE_IN * H];
    __shared__ float sx[4][NODE_IN];
    int tid = threadIdx.x;
    int lane = tid & 63;
    int w = tid >> 6;
    int n = blockIdx.x * 4 + w;
    for (int i = tid; i < NODE_IN * H; i += 256) sW[i] = Wenc[i];
    if (n < N_NODES && lane < NODE_IN) sx[w][lane] = x[n * NODE_IN + lane];
    __syncthreads();
    if (n < N_NODES){
        float acc = benc[lane];
        #pragma unroll
        for (int k = 0; k < NODE_IN; ++k)
            acc = fmaf(sx[w][k], sW[k * H + lane], acc);
        h[n * H + lane] = acc;
        hbf[n * H + lane] = f2bf(acc);
    }
}

// ------------- MFMA SAGE layer v8: 8-lanes/edge 16B gather, 4 blocks/CU -------------
// A = [mean | max | h] : [32 rows][192 k] bf16, stride 200
// W = [Wl ; Wr] stacked [192 k][64 f], bf16, transposed [f][k], stride 200
// LDS: sAh 12800 + sW 25600 + sRed 1024 = 39424B -> 4 blocks/CU
#define NT 32
__global__ __launch_bounds__(512, 8) void k_sage_mfma(const float* __restrict__ h,
    const ushort* __restrict__ hbf,
    const int* __restrict__ rs, const int* __restrict__ csr,
    const float* __restrict__ Wl, const float* __restrict__ bl, const float* __restrict__ Wr,
    const float* __restrict__ lng, const float* __restrict__ lnb,
    float* __restrict__ hout, ushort* __restrict__ hbfout)
{
    __shared__ __align__(16) ushort sAh[NT * 200];
    __shared__ __align__(16) ushort sW[64 * 200];
    __shared__ float2 sRed[8][16];
    const int tid = threadIdx.x;
    const int lane = tid & 63;
    const int w = tid >> 6;
    const int l15 = lane & 15;
    const int kb = lane >> 4;
    const int es = lane >> 3;      // 0..7 edge slot (gather)
    const int c8 = (lane & 7) * 8; // 8-feature chunk (gather)
    const int c4 = l15 * 4;        // 4-feature chunk (h staging)
    const int n0 = blockIdx.x * NT;

    for (int i = tid; i < 128 * 64; i += 512){
        int k = i >> 6, f = i & 63;
        sW[f * 200 + k] = f2bf(Wl[i]);
    }
    for (int i = tid; i < 64 * 64; i += 512){
        int k = (i >> 6) + 128, f = i & 63;
        sW[f * 200 + k] = f2bf(Wr[i]);
    }

    // ---- gather: wave w handles 4 nodes; 8 edges per 16B load ----
    for (int i = 0; i < 4; ++i){
        int nl = (w << 2) + i;
        int n = n0 + nl;
        float s[8], m[8];
        #pragma unroll
        for (int q = 0; q < 8; ++q){ s[q] = 0.f; m[q] = -INFINITY; }
        int dg = 0;
        float4 hv4 = make_float4(0.f, 0.f, 0.f, 0.f);
        if (n < N_NODES){
            int start = rs[n], end = rs[n + 1];
            dg = end - start;
            hv4 = *(const float4*)(h + (size_t)n * H + c4);
            const int* cp = csr + start;
            int nfull = dg >> 3;
            #pragma unroll 2
            for (int j = 0; j < nfull; ++j){
                int src = cp[j * 8 + es];
                const short8b u = *(const short8b*)(hbf + ((size_t)src << 6) + c8);
                #pragma unroll
                for (int q = 0; q < 8; ++q){
                    float v = bf2f((ushort)u[q]);
                    s[q] += v;
                    m[q] = fmaxf(m[q], v);
                }
            }
            int rem = dg & 7;
            if (rem){
                int e = nfull * 8 + es;
                int src = cp[(es < rem) ? e : 0];
                const short8b u = *(const short8b*)(hbf + ((size_t)src << 6) + c8);
                bool val = es < rem;
                #pragma unroll
                for (int q = 0; q < 8; ++q){
                    float v = bf2f((ushort)u[q]);
                    s[q] += val ? v : 0.f;
                    m[q] = fmaxf(m[q], val ? v : -INFINITY);
                }
            }
        }
        // butterfly over edge slots (lane bits 3..5) -> every lane holds full reduction
        #pragma unroll
        for (int off = 8; off < 64; off <<= 1){
            #pragma unroll
            for (int q = 0; q < 8; ++q){
                s[q] += __shfl_xor(s[q], off, 64);
                m[q] = fmaxf(m[q], __shfl_xor(m[q], off, 64));
            }
        }
        float inv = (dg > 0) ? (1.f / (float)dg) : 0.f;
        if (lane < 8){           // mean, feats c8..c8+7
            short8b o;
            #pragma unroll
            for (int q = 0; q < 8; ++q) o[q] = (short)f2bf(s[q] * inv);
            *(short8b*)(sAh + nl * 200 + c8) = o;
        } else if (lane < 16){   // max
            short8b o;
            #pragma unroll
            for (int q = 0; q < 8; ++q) o[q] = (short)f2bf((dg > 0) ? m[q] : 0.f);
            *(short8b*)(sAh + nl * 200 + 64 + c8) = o;
        } else if (lane < 32){   // own h row, feats c4..c4+3
            ushort4 o = { f2bf(hv4.x), f2bf(hv4.y), f2bf(hv4.z), f2bf(hv4.w) };
            *(ushort4*)(sAh + nl * 200 + 128 + c4) = o;
        }
    }
    __syncthreads();

    // ---- MFMA: wave w -> row-tile (w&1)*16, col-tile (w>>1)*16 ----
    f32x4 acc = (f32x4){0.f,0.f,0.f,0.f};
    const int rt = w & 1;
    const int c0 = (w >> 1) * 16;
    const int arow = (rt * 16 + l15) * 200 + kb * 8;
    const int brow = (c0 + l15) * 200 + kb * 8;
    #pragma unroll
    for (int kc = 0; kc < 6; ++kc){
        short8b ah = *(const short8b*)(sAh + arow + kc * 32);
        short8b b  = *(const short8b*)(sW + brow + kc * 32);
        acc = __builtin_amdgcn_mfma_f32_16x16x32_bf16(ah, b, acc, 0, 0, 0);
    }

    const int f = c0 + l15;
    float blf = bl[f], gf = lng[f], bfv = lnb[f];
    #pragma unroll
    for (int r = 0; r < 4; ++r) acc[r] += blf;
    f32x4 s1v, s2v;
    #pragma unroll
    for (int r = 0; r < 4; ++r){ s1v[r] = acc[r]; s2v[r] = acc[r] * acc[r]; }
    #pragma unroll
    for (int r = 0; r < 4; ++r){
        #pragma unroll
        for (int off = 1; off < 16; off <<= 1){
            s1v[r] += __shfl_xor(s1v[r], off, 64);
            s2v[r] += __shfl_xor(s2v[r], off, 64);
        }
    }
    if (l15 == 0){
        #pragma unroll
        for (int r = 0; r < 4; ++r) sRed[w][kb * 4 + r] = make_float2(s1v[r], s2v[r]);
    }
    __syncthreads();
    const int rowb = n0 + rt * 16 + kb * 4;
    #pragma unroll
    for (int r = 0; r < 4; ++r){
        int row = rowb + r;
        if (row < N_NODES){
            float2 p2 = sRed[w ^ 2][kb * 4 + r];
            float2 p4 = sRed[w ^ 4][kb * 4 + r];
            float2 p6 = sRed[w ^ 6][kb * 4 + r];
            float S1 = s1v[r] + p2.x + p4.x + p6.x;
            float S2 = s2v[r] + p2.y + p4.y + p6.y;
            float mu = S1 * (1.f / 64.f);
            float var = S2 * (1.f / 64.f) - mu * mu;
            float rsv = rsqrtf(var + LN_EPS);
            float y = (acc[r] - mu) * rsv * gf + bfv;
            float o = gelu_f(y) + h[row * H + f];
            hout[row * H + f] = o;
            hbfout[row * H + f] = f2bf(o);
        }
    }
}

// ------------- persistent-weight MFMA edge MLP -------------
#define QB2 64
#define MLP_TILES (N_QUERY / QB2)
#define MLP_GRID 512
__global__ __launch_bounds__(512, 2) void k_mlp2(const ushort* __restrict__ hbf,
    const int* __restrict__ qe, const float* __restrict__ ea,
    const float* __restrict__ W1, const float* __restrict__ b1,
    const float* __restrict__ bng, const float* __restrict__ bnb,
    const float* __restrict__ bnm, const float* __restrict__ bnv,
    const float* __restrict__ W2, const float* __restrict__ b2,
    const float* __restrict__ W3, const float* __restrict__ b3,
    float* __restrict__ out)
{
    __shared__ __align__(16) ushort sW1[128 * 136 + 32];
    __shared__ __align__(16) ushort sW2[64 * 136];
    __shared__ __align__(16) ushort sZ[QB2 * 168];
    __shared__ float sRedO[8][16];
    const int tid = threadIdx.x;
    const int lane = tid & 63;
    const int w = tid >> 6;
    const int l15 = lane & 15;
    const int kb = lane >> 4;
    const int rt = w & 3;
    const int whalf = w >> 2;

    for (int i = tid; i < 136 * 128; i += 512){
        int k = i >> 7, j = i & 127;
        sW1[j * 136 + k] = f2bf(W1[i]);
    }
    if (tid < 32) sW1[128 * 136 + tid] = 0;
    for (int i = tid; i < 64 * 128; i += 512){
        int k = i >> 6, f = i & 63;
        sW2[f * 136 + k] = f2bf(W2[i]);
    }
    float scn[4], shn[4];
    #pragma unroll
    for (int n = 0; n < 4; ++n){
        int j = whalf * 64 + n * 16 + l15;
        float sc = bng[j] * rsqrtf(bnv[j] + BN_EPS);
        scn[n] = sc;
        shn[n] = bnb[j] - bnm[j] * sc + b1[j] * sc;
    }
    float b2f[2], w3f[2];
    #pragma unroll
    for (int n = 0; n < 2; ++n){
        int f = whalf * 32 + n * 16 + l15;
        b2f[n] = b2[f]; w3f[n] = W3[f];
    }
    float b3v = b3[0];
    __syncthreads();

    for (int t = blockIdx.x; t < MLP_TILES; t += MLP_GRID){
        int q0 = t * QB2;
        {
            int tq = tid >> 3, part = tid & 7;
            int q = q0 + tq;
            ushort* dst = sZ + tq * 168;
            if (part < 4){
                int sidx = qe[q];
                const ushort* src = hbf + (size_t)sidx * H + part * 16;
                *(short8b*)(dst + part * 16)     = *(const short8b*)(src);
                *(short8b*)(dst + part * 16 + 8) = *(const short8b*)(src + 8);
            } else {
                int tidx = qe[N_QUERY + q];
                const ushort* src = hbf + (size_t)tidx * H + (part - 4) * 16;
                *(short8b*)(dst + 64 + (part - 4) * 16)     = *(const short8b*)(src);
                *(short8b*)(dst + 64 + (part - 4) * 16 + 8) = *(const short8b*)(src + 8);
                ushort4 zz = { 0, 0, 0, 0 };
                *(ushort4*)(dst + 136 + (part - 4) * 8)     = zz;
                *(ushort4*)(dst + 136 + (part - 4) * 8 + 4) = zz;
            }
            if (part == 0){
                const float4* ep = (const float4*)(ea + (size_t)q * 8);
                float4 e0 = ep[0], e1 = ep[1];
                ushort4 o0 = { f2bf(e0.x), f2bf(e0.y), f2bf(e0.z), f2bf(e0.w) };
                ushort4 o1 = { f2bf(e1.x), f2bf(e1.y), f2bf(e1.z), f2bf(e1.w) };
                *(ushort4*)(dst + 128) = o0;
                *(ushort4*)(dst + 132) = o1;
            }
        }
        __syncthreads();

        f32x4 acc[4];
        #pragma unroll
        for (int n = 0; n < 4; ++n) acc[n] = (f32x4){0.f, 0.f, 0.f, 0.f};
        const int arow = (rt * 16 + l15) * 168 + kb * 8;
        #pragma unroll
        for (int kc = 0; kc < 5; ++kc){
            short8b a = *(const short8b*)(sZ + arow + kc * 32);
            #pragma unroll
            for (int n = 0; n < 4; ++n){
                int j = whalf * 64 + n * 16 + l15;
                short8b b = *(const short8b*)(sW1 + j * 136 + kc * 32 + kb * 8);
                acc[n] = __builtin_amdgcn_mfma_f32_16x16x32_bf16(a, b, acc[n], 0, 0, 0);
            }
        }
        __syncthreads();
        #pragma unroll
        for (int n = 0; n < 4; ++n){
            #pragma unroll
            for (int r = 0; r < 4; ++r){
                float v = acc[n][r] * scn[n] + shn[n];
                sZ[(rt * 16 + kb * 4 + r) * 136 + whalf * 64 + n * 16 + l15] = f2bf(gelu_f(v));
            }
        }
        __syncthreads();

        f32x4 acc2[2];
        acc2[0] = (f32x4){0.f,0.f,0.f,0.f};
        acc2[1] = (f32x4){0.f,0.f,0.f,0.f};
        const int arow2 = (rt * 16 + l15) * 136 + kb * 8;
        #pragma unroll
        for (int s = 0; s < 4; ++s){
            short8b a = *(const short8b*)(sZ + arow2 + s * 32);
            #pragma unroll
            for (int n = 0; n < 2; ++n){
                int f = whalf * 32 + n * 16 + l15;
                short8b b = *(const short8b*)(sW2 + f * 136 + s * 32 + kb * 8);
                acc2[n] = __builtin_amdgcn_mfma_f32_16x16x32_bf16(a, b, acc2[n], 0, 0, 0);
            }
        }
        f32x4 pv = (f32x4){0.f,0.f,0.f,0.f};
        #pragma unroll
        for (int n = 0; n < 2; ++n){
            #pragma unroll
            for (int r = 0; r < 4; ++r)
                pv[r] += gelu_f(acc2[n][r] + b2f[n]) * w3f[n];
        }
        #pragma unroll
        for (int r = 0; r < 4; ++r){
            #pragma unroll
            for (int off = 1; off < 16; off <<= 1)
                pv[r] += __shfl_xor(pv[r], off, 64);
        }
        if (l15 == 0){
            #pragma unroll
            for (int r = 0; r < 4; ++r) sRedO[w][kb * 4 + r] = pv[r];
        }
        __syncthreads();
        if (whalf == 0 && l15 == 0){
            #pragma unroll
            for (int r = 0; r < 4; ++r){
                int q = q0 + rt * 16 + kb * 4 + r;
                out[q] = pv[r] + sRedO[w ^ 4][kb * 4 + r] + b3v;
            }
        }
        __syncthreads();
    }
}

extern "C" void kernel_launch(void* const* d_in, const int* in_sizes, int n_in,
                              void* d_out, int out_size, void* d_ws, size_t ws_size,
                              hipStream_t stream) {
    const float* x    = (const float*)d_in[0];
    const int*   ei   = (const int*)d_in[1];
    const float* ea   = (const float*)d_in[2];
    const int*   qe   = (const int*)d_in[3];
    const float* Wenc = (const float*)d_in[4];
    const float* benc = (const float*)d_in[5];
    const float* Wl   = (const float*)d_in[6];
    const float* bl   = (const float*)d_in[7];
    const float* Wr   = (const float*)d_in[8];
    const float* lng  = (const float*)d_in[9];
    const float* lnb  = (const float*)d_in[10];
    const float* W1   = (const float*)d_in[11];
    const float* b1   = (const float*)d_in[12];
    const float* bng  = (const float*)d_in[13];
    const float* bnb  = (const float*)d_in[14];
    const float* bnm  = (const float*)d_in[15];
    const float* bnv  = (const float*)d_in[16];
    const float* W2   = (const float*)d_in[17];
    const float* b2   = (const float*)d_in[18];
    const float* W3   = (const float*)d_in[19];
    const float* b3   = (const float*)d_in[20];
    float* out = (float*)d_out;

    char* ws = (char*)d_ws;
    const size_t NH = (size_t)N_NODES * H;
    float*  hA   = (float*)ws;   ws += NH * 4;
    float*  hB   = (float*)ws;   ws += NH * 4;
    ushort* hbfA = (ushort*)ws;  ws += NH * 2;
    ushort* hbfB = (ushort*)ws;  ws += NH * 2;
    int*    cnt  = (int*)ws;     ws += (size_t)N_NODES * 4;
    int*    rsb  = (int*)ws;     ws += ((size_t)N_NODES + 4) * 4;
    int*    bcur = (int*)ws;     ws += (size_t)NBUK * 4;
    int*    csr  = (int*)ws;     ws += (size_t)N_EDGES * 4;
    int*    bsum = (int*)ws;     ws += 512 * 4;

    // CSR build (bucketed, wave-coalesced writes)
    hipMemsetAsync(cnt, 0, (size_t)N_NODES * 4, stream);
    k_count<<<(N_EDGES + 255) / 256, 256, 0, stream>>>(ei, cnt);
    k_scanA<<<NBLK, 256, 0, stream>>>(cnt, bsum);
    k_scanB<<<1, 512, 0, stream>>>(bsum);
    k_scanC<<<NBLK, 256, 0, stream>>>(cnt, bsum, rsb, bcur);
    k_bucketA<<<(N_EDGES + ACHUNK - 1) / ACHUNK, 1024, 0, stream>>>(ei, bcur, csr);
    k_fillB<<<NBUK, 1024, 0, stream>>>(rsb, csr);

    // encoder
    k_enc<<<(N_NODES + 3) / 4, 256, 0, stream>>>(x, Wenc, benc, hA, hbfA);

    // SAGE layers (MFMA, NT=32, 4 blocks/CU)
    int nbn = (N_NODES + NT - 1) / NT;
    float* hc = hA;  float* hn = hB;
    ushort* hbc = hbfA; ushort* hbn = hbfB;
    for (int l = 0; l < LAYERS; ++l){
        k_sage_mfma<<<nbn, 512, 0, stream>>>(hc, hbc, rsb, csr,
            Wl + (size_t)l * 2 * H * H, bl + l * H, Wr + (size_t)l * H * H,
            lng + l * H, lnb + l * H, hn, hbn);
        float* t1 = hc; hc = hn; hn = t1;
        ushort* t2 = hbc; hbc = hbn; hbn = t2;
    }

    // edge MLP (persistent weights)
    k_mlp2<<<MLP_GRID, 512, 0, stream>>>(hbc, qe, ea, W1, b1, bng, bnb, bnm, bnv, W2, b2, W3, b3, out);
}

// Round 17
// 453.370 us; speedup vs baseline: 1.0666x; 1.0666x over previous
//
#include <hip/hip_runtime.h>
#include <math.h>

#define N_NODES 100000
#define N_EDGES 1600000
#define N_QUERY 200000
#define NODE_IN 32
#define EDGE_IN 8
#define H 64
#define LAYERS 3
#define LN_EPS 1e-5f
#define BN_EPS 1e-5f
#define NBLK 391
#define NBUK 391
#define ACHUNK 4096
#define CAPB 6144

typedef __attribute__((ext_vector_type(8))) short short8b;
typedef __attribute__((ext_vector_type(4))) float f32x4;

__device__ __forceinline__ float gelu_f(float x){
    return 0.5f * x * (1.0f + erff(x * 0.70710678118654752440f));
}
__device__ __forceinline__ ushort f2bf(float x){  // RNE f32->bf16
    unsigned u = __float_as_uint(x);
    unsigned r = (u + 0x7FFFu + ((u >> 16) & 1u)) >> 16;
    return (ushort)r;
}
__device__ __forceinline__ float bf2f(ushort x){
    return __uint_as_float(((unsigned)x) << 16);
}

// ---------------- CSR build (bucketed) ----------------
__global__ __launch_bounds__(256) void k_count(const int* __restrict__ ei, int* __restrict__ c){
    int i = blockIdx.x * 256 + threadIdx.x;
    if (i < N_EDGES) atomicAdd(&c[ei[N_EDGES + i]], 1);
}
__global__ __launch_bounds__(256) void k_scanA(const int* __restrict__ cnt, int* __restrict__ bsum){
    int i = blockIdx.x * 256 + threadIdx.x;
    int v = (i < N_NODES) ? cnt[i] : 0;
    #pragma unroll
    for (int off = 32; off; off >>= 1) v += __shfl_xor(v, off, 64);
    __shared__ int ws[4];
    if ((threadIdx.x & 63) == 0) ws[threadIdx.x >> 6] = v;
    __syncthreads();
    if (threadIdx.x == 0) bsum[blockIdx.x] = ws[0] + ws[1] + ws[2] + ws[3];
}
__global__ __launch_bounds__(512) void k_scanB(int* __restrict__ bsum){
    __shared__ int s[512];
    int t = threadIdx.x;
    int v = (t < NBLK) ? bsum[t] : 0;
    s[t] = v; __syncthreads();
    for (int off = 1; off < 512; off <<= 1){
        int u = (t >= off) ? s[t - off] : 0;
        __syncthreads();
        s[t] += u;
        __syncthreads();
    }
    if (t < NBLK) bsum[t] = s[t] - v;
}
__global__ __launch_bounds__(256) void k_scanC(const int* __restrict__ cnt, const int* __restrict__ bsum,
                                               int* __restrict__ rs, int* __restrict__ bcur){
    __shared__ int s[256];
    int t = threadIdx.x;
    int i = blockIdx.x * 256 + t;
    int v = (i < N_NODES) ? cnt[i] : 0;
    s[t] = v; __syncthreads();
    for (int off = 1; off < 256; off <<= 1){
        int u = (t >= off) ? s[t - off] : 0;
        __syncthreads();
        s[t] += u;
        __syncthreads();
    }
    int pref = bsum[blockIdx.x] + s[t] - v;
    if (i < N_NODES) rs[i] = pref;
    if (i == N_NODES - 1) rs[N_NODES] = pref + v;
    if (t == 0) bcur[blockIdx.x] = bsum[blockIdx.x];
}
__global__ __launch_bounds__(1024) void k_bucketA(const int* __restrict__ ei, int* __restrict__ bcur,
                                                  int* __restrict__ bucketed){
    __shared__ int hist[NBUK], pref[NBUK], curl[NBUK], gbase[NBUK];
    __shared__ int scan[512];
    __shared__ int stageP[ACHUNK];
    __shared__ ushort stageB[ACHUNK];
    int tid = threadIdx.x;
    int e0 = blockIdx.x * ACHUNK;
    int cnt = N_EDGES - e0;
    if (cnt > ACHUNK) cnt = ACHUNK;
    for (int b = tid; b < NBUK; b += 1024) hist[b] = 0;
    __syncthreads();
    int myd[4], mys[4];
    #pragma unroll
    for (int i = 0; i < 4; ++i){
        int idx = tid + i * 1024;
        if (idx < cnt){
            int e = e0 + idx;
            mys[i] = ei[e];
            myd[i] = ei[N_EDGES + e];
            atomicAdd(&hist[myd[i] >> 8], 1);
        } else myd[i] = -1;
    }
    __syncthreads();
    int v = (tid < NBUK) ? hist[tid] : 0;
    if (tid < 512) scan[tid] = v;
    __syncthreads();
    for (int off = 1; off < 512; off <<= 1){
        int u = 0;
        if (tid < 512 && tid >= off) u = scan[tid - off];
        __syncthreads();
        if (tid < 512) scan[tid] += u;
        __syncthreads();
    }
    if (tid < NBUK){
        int ex = scan[tid] - v;
        pref[tid] = ex;
        curl[tid] = ex;
        if (v > 0) gbase[tid] = atomicAdd(&bcur[tid], v);
    }
    __syncthreads();
    #pragma unroll
    for (int i = 0; i < 4; ++i){
        if (myd[i] >= 0){
            int b = myd[i] >> 8;
            int p = atomicAdd(&curl[b], 1);
            stageP[p] = (mys[i] << 8) | (myd[i] & 255);
            stageB[p] = (ushort)b;
        }
    }
    __syncthreads();
    for (int p = tid; p < cnt; p += 1024){
        int b = stageB[p];
        bucketed[gbase[b] + (p - pref[b])] = stageP[p];
    }
}
__global__ __launch_bounds__(1024) void k_fillB(const int* __restrict__ rs, int* __restrict__ csr){
    __shared__ int packed[CAPB];
    __shared__ int sorted[CAPB];
    __shared__ int hist[256], cur[256];
    __shared__ int scan[256];
    int tid = threadIdx.x;
    int node0 = blockIdx.x * 256;
    int node1 = node0 + 256; if (node1 > N_NODES) node1 = N_NODES;
    int r0 = rs[node0], r1 = rs[node1];
    int L = r1 - r0;
    if (tid < 256) hist[tid] = 0;
    __syncthreads();
    for (int i = tid; i < L; i += 1024){
        int pk = csr[r0 + i];
        packed[i] = pk;
        atomicAdd(&hist[pk & 255], 1);
    }
    __syncthreads();
    int v = (tid < 256) ? hist[tid] : 0;
    if (tid < 256) scan[tid] = v;
    __syncthreads();
    for (int off = 1; off < 256; off <<= 1){
        int u = 0;
        if (tid < 256 && tid >= off) u = scan[tid - off];
        __syncthreads();
        if (tid < 256) scan[tid] += u;
        __syncthreads();
    }
    if (tid < 256) cur[tid] = scan[tid] - v;
    __syncthreads();
    for (int i = tid; i < L; i += 1024){
        int pk = packed[i];
        int p = atomicAdd(&cur[pk & 255], 1);
        sorted[p] = pk >> 8;
    }
    __syncthreads();
    for (int i = tid; i < L; i += 1024) csr[r0 + i] = sorted[i];
}

// ---------------- node encoder (f32 + flat bf16 mirror) ----------------
__global__ __launch_bounds__(256) void k_enc(const float* __restrict__ x, const float* __restrict__ Wenc,
                                             const float* __restrict__ benc, float* __restrict__ h,
                                             ushort* __restrict__ hbf){
    __shared__ __align__(16) float sW[NODE_IN * H];
    __shared__ float sx[4][NODE_IN];
    int tid = threadIdx.x;
    int lane = tid & 63;
    int w = tid >> 6;
    int n = blockIdx.x * 4 + w;
    for (int i = tid; i < NODE_IN * H; i += 256) sW[i] = Wenc[i];
    if (n < N_NODES && lane < NODE_IN) sx[w][lane] = x[n * NODE_IN + lane];
    __syncthreads();
    if (n < N_NODES){
        float acc = benc[lane];
        #pragma unroll
        for (int k = 0; k < NODE_IN; ++k)
            acc = fmaf(sx[w][k], sW[k * H + lane], acc);
        h[n * H + lane] = acc;
        hbf[n * H + lane] = f2bf(acc);
    }
}

// ------------- MFMA SAGE layer v9: r15 gather (8B/4-edge), NT=64, 1024 thr, 2 blocks/CU (32 waves) -------------
// A = [mean | max | h] : [64 rows][192 k] bf16, stride 200
// W = [Wl ; Wr] stacked [192 k][64 f], bf16, transposed [f][k], stride 200
// LDS: sAh 25600 + sW 25600 + sRed 2048 = 53248B -> 2 blocks/CU = 32 waves/CU
#define NT 64
__global__ __launch_bounds__(1024, 8) void k_sage_mfma(const float* __restrict__ h,
    const ushort* __restrict__ hbf,
    const int* __restrict__ rs, const int* __restrict__ csr,
    const float* __restrict__ Wl, const float* __restrict__ bl, const float* __restrict__ Wr,
    const float* __restrict__ lng, const float* __restrict__ lnb,
    float* __restrict__ hout, ushort* __restrict__ hbfout)
{
    __shared__ __align__(16) ushort sAh[NT * 200];
    __shared__ __align__(16) ushort sW[64 * 200];
    __shared__ float2 sRed[16][16];
    const int tid = threadIdx.x;
    const int lane = tid & 63;
    const int w = tid >> 6;        // wave 0..15
    const int l15 = lane & 15;
    const int kb = lane >> 4;      // 0..3 (edge group in gather, k-block in MFMA)
    const int c4 = l15 * 4;        // 4-feature chunk
    const int n0 = blockIdx.x * NT;

    for (int i = tid; i < 128 * 64; i += 1024){
        int k = i >> 6, f = i & 63;
        sW[f * 200 + k] = f2bf(Wl[i]);
    }
    for (int i = tid; i < 64 * 64; i += 1024){
        int k = (i >> 6) + 128, f = i & 63;
        sW[f * 200 + k] = f2bf(Wr[i]);
    }

    // ---- gather: wave w handles 4 nodes; 4 edges per 8B bf16 load ----
    for (int i = 0; i < 4; ++i){
        int nl = (w << 2) + i;
        int n = n0 + nl;
        float s0 = 0.f, s1 = 0.f, s2 = 0.f, s3 = 0.f;
        float m0 = -INFINITY, m1 = -INFINITY, m2 = -INFINITY, m3 = -INFINITY;
        int dg = 0;
        float4 hv4 = make_float4(0.f, 0.f, 0.f, 0.f);
        if (n < N_NODES){
            int start = rs[n], end = rs[n + 1];
            dg = end - start;
            hv4 = *(const float4*)(h + (size_t)n * H + c4);
            const int* cp = csr + start;
            int nfull = dg >> 2;
            #pragma unroll 4
            for (int j = 0; j < nfull; ++j){
                int s = cp[j * 4 + kb];
                const ushort4 u = *(const ushort4*)(hbf + ((size_t)s << 6) + c4);
                float v0 = bf2f(u.x), v1 = bf2f(u.y), v2 = bf2f(u.z), v3 = bf2f(u.w);
                s0 += v0; s1 += v1; s2 += v2; s3 += v3;
                m0 = fmaxf(m0, v0); m1 = fmaxf(m1, v1);
                m2 = fmaxf(m2, v2); m3 = fmaxf(m3, v3);
            }
            int rem = dg & 3;
            if (rem){
                int e = nfull * 4 + kb;
                int s = cp[(kb < rem) ? e : 0];
                const ushort4 u = *(const ushort4*)(hbf + ((size_t)s << 6) + c4);
                float v0 = bf2f(u.x), v1 = bf2f(u.y), v2 = bf2f(u.z), v3 = bf2f(u.w);
                bool val = kb < rem;
                s0 += val ? v0 : 0.f;  s1 += val ? v1 : 0.f;
                s2 += val ? v2 : 0.f;  s3 += val ? v3 : 0.f;
                m0 = fmaxf(m0, val ? v0 : -INFINITY);
                m1 = fmaxf(m1, val ? v1 : -INFINITY);
                m2 = fmaxf(m2, val ? v2 : -INFINITY);
                m3 = fmaxf(m3, val ? v3 : -INFINITY);
            }
        }
        #pragma unroll
        for (int off = 16; off < 64; off <<= 1){
            s0 += __shfl_xor(s0, off, 64); s1 += __shfl_xor(s1, off, 64);
            s2 += __shfl_xor(s2, off, 64); s3 += __shfl_xor(s3, off, 64);
            m0 = fmaxf(m0, __shfl_xor(m0, off, 64)); m1 = fmaxf(m1, __shfl_xor(m1, off, 64));
            m2 = fmaxf(m2, __shfl_xor(m2, off, 64)); m3 = fmaxf(m3, __shfl_xor(m3, off, 64));
        }
        float inv = (dg > 0) ? (1.f / (float)dg) : 0.f;
        float4 val;
        if (kb == 0)      val = make_float4(s0 * inv, s1 * inv, s2 * inv, s3 * inv);
        else if (kb == 1) val = (dg > 0) ? make_float4(m0, m1, m2, m3) : make_float4(0.f,0.f,0.f,0.f);
        else              val = hv4;
        if (kb < 3){
            ushort4 vh = { f2bf(val.x), f2bf(val.y), f2bf(val.z), f2bf(val.w) };
            *(ushort4*)(sAh + nl * 200 + kb * 64 + c4) = vh;
        }
    }
    __syncthreads();

    // ---- MFMA: wave w -> row-tile (w&3)*16, col-tile (w>>2)*16 ----
    f32x4 acc = (f32x4){0.f,0.f,0.f,0.f};
    const int rt = w & 3;
    const int c0 = (w >> 2) * 16;
    const int arow = (rt * 16 + l15) * 200 + kb * 8;
    const int brow = (c0 + l15) * 200 + kb * 8;
    #pragma unroll
    for (int kc = 0; kc < 6; ++kc){
        short8b ah = *(const short8b*)(sAh + arow + kc * 32);
        short8b b  = *(const short8b*)(sW + brow + kc * 32);
        acc = __builtin_amdgcn_mfma_f32_16x16x32_bf16(ah, b, acc, 0, 0, 0);
    }

    const int f = c0 + l15;
    float blf = bl[f], gf = lng[f], bfv = lnb[f];
    #pragma unroll
    for (int r = 0; r < 4; ++r) acc[r] += blf;
    f32x4 s1v, s2v;
    #pragma unroll
    for (int r = 0; r < 4; ++r){ s1v[r] = acc[r]; s2v[r] = acc[r] * acc[r]; }
    #pragma unroll
    for (int r = 0; r < 4; ++r){
        #pragma unroll
        for (int off = 1; off < 16; off <<= 1){
            s1v[r] += __shfl_xor(s1v[r], off, 64);
            s2v[r] += __shfl_xor(s2v[r], off, 64);
        }
    }
    if (l15 == 0){
        #pragma unroll
        for (int r = 0; r < 4; ++r) sRed[w][kb * 4 + r] = make_float2(s1v[r], s2v[r]);
    }
    __syncthreads();
    const int rowb = n0 + rt * 16 + kb * 4;
    #pragma unroll
    for (int r = 0; r < 4; ++r){
        int row = rowb + r;
        if (row < N_NODES){
            float2 p4 = sRed[w ^ 4][kb * 4 + r];
            float2 p8 = sRed[w ^ 8][kb * 4 + r];
            float2 pC = sRed[w ^ 12][kb * 4 + r];
            float S1 = s1v[r] + p4.x + p8.x + pC.x;
            float S2 = s2v[r] + p4.y + p8.y + pC.y;
            float mu = S1 * (1.f / 64.f);
            float var = S2 * (1.f / 64.f) - mu * mu;
            float rsv = rsqrtf(var + LN_EPS);
            float y = (acc[r] - mu) * rsv * gf + bfv;
            float o = gelu_f(y) + h[row * H + f];
            hout[row * H + f] = o;
            hbfout[row * H + f] = f2bf(o);
        }
    }
}

// ------------- persistent-weight MFMA edge MLP -------------
#define QB2 64
#define MLP_TILES (N_QUERY / QB2)
#define MLP_GRID 512
__global__ __launch_bounds__(512, 2) void k_mlp2(const ushort* __restrict__ hbf,
    const int* __restrict__ qe, const float* __restrict__ ea,
    const float* __restrict__ W1, const float* __restrict__ b1,
    const float* __restrict__ bng, const float* __restrict__ bnb,
    const float* __restrict__ bnm, const float* __restrict__ bnv,
    const float* __restrict__ W2, const float* __restrict__ b2,
    const float* __restrict__ W3, const float* __restrict__ b3,
    float* __restrict__ out)
{
    __shared__ __align__(16) ushort sW1[128 * 136 + 32];
    __shared__ __align__(16) ushort sW2[64 * 136];
    __shared__ __align__(16) ushort sZ[QB2 * 168];
    __shared__ float sRedO[8][16];
    const int tid = threadIdx.x;
    const int lane = tid & 63;
    const int w = tid >> 6;
    const int l15 = lane & 15;
    const int kb = lane >> 4;
    const int rt = w & 3;
    const int whalf = w >> 2;

    for (int i = tid; i < 136 * 128; i += 512){
        int k = i >> 7, j = i & 127;
        sW1[j * 136 + k] = f2bf(W1[i]);
    }
    if (tid < 32) sW1[128 * 136 + tid] = 0;
    for (int i = tid; i < 64 * 128; i += 512){
        int k = i >> 6, f = i & 63;
        sW2[f * 136 + k] = f2bf(W2[i]);
    }
    float scn[4], shn[4];
    #pragma unroll
    for (int n = 0; n < 4; ++n){
        int j = whalf * 64 + n * 16 + l15;
        float sc = bng[j] * rsqrtf(bnv[j] + BN_EPS);
        scn[n] = sc;
        shn[n] = bnb[j] - bnm[j] * sc + b1[j] * sc;
    }
    float b2f[2], w3f[2];
    #pragma unroll
    for (int n = 0; n < 2; ++n){
        int f = whalf * 32 + n * 16 + l15;
        b2f[n] = b2[f]; w3f[n] = W3[f];
    }
    float b3v = b3[0];
    __syncthreads();

    for (int t = blockIdx.x; t < MLP_TILES; t += MLP_GRID){
        int q0 = t * QB2;
        {
            int tq = tid >> 3, part = tid & 7;
            int q = q0 + tq;
            ushort* dst = sZ + tq * 168;
            if (part < 4){
                int sidx = qe[q];
                const ushort* src = hbf + (size_t)sidx * H + part * 16;
                *(short8b*)(dst + part * 16)     = *(const short8b*)(src);
                *(short8b*)(dst + part * 16 + 8) = *(const short8b*)(src + 8);
            } else {
                int tidx = qe[N_QUERY + q];
                const ushort* src = hbf + (size_t)tidx * H + (part - 4) * 16;
                *(short8b*)(dst + 64 + (part - 4) * 16)     = *(const short8b*)(src);
                *(short8b*)(dst + 64 + (part - 4) * 16 + 8) = *(const short8b*)(src + 8);
                ushort4 zz = { 0, 0, 0, 0 };
                *(ushort4*)(dst + 136 + (part - 4) * 8)     = zz;
                *(ushort4*)(dst + 136 + (part - 4) * 8 + 4) = zz;
            }
            if (part == 0){
                const float4* ep = (const float4*)(ea + (size_t)q * 8);
                float4 e0 = ep[0], e1 = ep[1];
                ushort4 o0 = { f2bf(e0.x), f2bf(e0.y), f2bf(e0.z), f2bf(e0.w) };
                ushort4 o1 = { f2bf(e1.x), f2bf(e1.y), f2bf(e1.z), f2bf(e1.w) };
                *(ushort4*)(dst + 128) = o0;
                *(ushort4*)(dst + 132) = o1;
            }
        }
        __syncthreads();

        f32x4 acc[4];
        #pragma unroll
        for (int n = 0; n < 4; ++n) acc[n] = (f32x4){0.f, 0.f, 0.f, 0.f};
        const int arow = (rt * 16 + l15) * 168 + kb * 8;
        #pragma unroll
        for (int kc = 0; kc < 5; ++kc){
            short8b a = *(const short8b*)(sZ + arow + kc * 32);
            #pragma unroll
            for (int n = 0; n < 4; ++n){
                int j = whalf * 64 + n * 16 + l15;
                short8b b = *(const short8b*)(sW1 + j * 136 + kc * 32 + kb * 8);
                acc[n] = __builtin_amdgcn_mfma_f32_16x16x32_bf16(a, b, acc[n], 0, 0, 0);
            }
        }
        __syncthreads();
        #pragma unroll
        for (int n = 0; n < 4; ++n){
            #pragma unroll
            for (int r = 0; r < 4; ++r){
                float v = acc[n][r] * scn[n] + shn[n];
                sZ[(rt * 16 + kb * 4 + r) * 136 + whalf * 64 + n * 16 + l15] = f2bf(gelu_f(v));
            }
        }
        __syncthreads();

        f32x4 acc2[2];
        acc2[0] = (f32x4){0.f,0.f,0.f,0.f};
        acc2[1] = (f32x4){0.f,0.f,0.f,0.f};
        const int arow2 = (rt * 16 + l15) * 136 + kb * 8;
        #pragma unroll
        for (int s = 0; s < 4; ++s){
            short8b a = *(const short8b*)(sZ + arow2 + s * 32);
            #pragma unroll
            for (int n = 0; n < 2; ++n){
                int f = whalf * 32 + n * 16 + l15;
                short8b b = *(const short8b*)(sW2 + f * 136 + s * 32 + kb * 8);
                acc2[n] = __builtin_amdgcn_mfma_f32_16x16x32_bf16(a, b, acc2[n], 0, 0, 0);
            }
        }
        f32x4 pv = (f32x4){0.f,0.f,0.f,0.f};
        #pragma unroll
        for (int n = 0; n < 2; ++n){
            #pragma unroll
            for (int r = 0; r < 4; ++r)
                pv[r] += gelu_f(acc2[n][r] + b2f[n]) * w3f[n];
        }
        #pragma unroll
        for (int r = 0; r < 4; ++r){
            #pragma unroll
            for (int off = 1; off < 16; off <<= 1)
                pv[r] += __shfl_xor(pv[r], off, 64);
        }
        if (l15 == 0){
            #pragma unroll
            for (int r = 0; r < 4; ++r) sRedO[w][kb * 4 + r] = pv[r];
        }
        __syncthreads();
        if (whalf == 0 && l15 == 0){
            #pragma unroll
            for (int r = 0; r < 4; ++r){
                int q = q0 + rt * 16 + kb * 4 + r;
                out[q] = pv[r] + sRedO[w ^ 4][kb * 4 + r] + b3v;
            }
        }
        __syncthreads();
    }
}

extern "C" void kernel_launch(void* const* d_in, const int* in_sizes, int n_in,
                              void* d_out, int out_size, void* d_ws, size_t ws_size,
                              hipStream_t stream) {
    const float* x    = (const float*)d_in[0];
    const int*   ei   = (const int*)d_in[1];
    const float* ea   = (const float*)d_in[2];
    const int*   qe   = (const int*)d_in[3];
    const float* Wenc = (const float*)d_in[4];
    const float* benc = (const float*)d_in[5];
    const float* Wl   = (const float*)d_in[6];
    const float* bl   = (const float*)d_in[7];
    const float* Wr   = (const float*)d_in[8];
    const float* lng  = (const float*)d_in[9];
    const float* lnb  = (const float*)d_in[10];
    const float* W1   = (const float*)d_in[11];
    const float* b1   = (const float*)d_in[12];
    const float* bng  = (const float*)d_in[13];
    const float* bnb  = (const float*)d_in[14];
    const float* bnm  = (const float*)d_in[15];
    const float* bnv  = (const float*)d_in[16];
    const float* W2   = (const float*)d_in[17];
    const float* b2   = (const float*)d_in[18];
    const float* W3   = (const float*)d_in[19];
    const float* b3   = (const float*)d_in[20];
    float* out = (float*)d_out;

    char* ws = (char*)d_ws;
    const size_t NH = (size_t)N_NODES * H;
    float*  hA   = (float*)ws;   ws += NH * 4;
    float*  hB   = (float*)ws;   ws += NH * 4;
    ushort* hbfA = (ushort*)ws;  ws += NH * 2;
    ushort* hbfB = (ushort*)ws;  ws += NH * 2;
    int*    cnt  = (int*)ws;     ws += (size_t)N_NODES * 4;
    int*    rsb  = (int*)ws;     ws += ((size_t)N_NODES + 4) * 4;
    int*    bcur = (int*)ws;     ws += (size_t)NBUK * 4;
    int*    csr  = (int*)ws;     ws += (size_t)N_EDGES * 4;
    int*    bsum = (int*)ws;     ws += 512 * 4;

    // CSR build (bucketed, wave-coalesced writes)
    hipMemsetAsync(cnt, 0, (size_t)N_NODES * 4, stream);
    k_count<<<(N_EDGES + 255) / 256, 256, 0, stream>>>(ei, cnt);
    k_scanA<<<NBLK, 256, 0, stream>>>(cnt, bsum);
    k_scanB<<<1, 512, 0, stream>>>(bsum);
    k_scanC<<<NBLK, 256, 0, stream>>>(cnt, bsum, rsb, bcur);
    k_bucketA<<<(N_EDGES + ACHUNK - 1) / ACHUNK, 1024, 0, stream>>>(ei, bcur, csr);
    k_fillB<<<NBUK, 1024, 0, stream>>>(rsb, csr);

    // encoder
    k_enc<<<(N_NODES + 3) / 4, 256, 0, stream>>>(x, Wenc, benc, hA, hbfA);

    // SAGE layers (MFMA, NT=64, 1024 threads, 2 blocks/CU)
    int nbn = (N_NODES + NT - 1) / NT;
    float* hc = hA;  float* hn = hB;
    ushort* hbc = hbfA; ushort* hbn = hbfB;
    for (int l = 0; l < LAYERS; ++l){
        k_sage_mfma<<<nbn, 1024, 0, stream>>>(hc, hbc, rsb, csr,
            Wl + (size_t)l * 2 * H * H, bl + l * H, Wr + (size_t)l * H * H,
            lng + l * H, lnb + l * H, hn, hbn);
        float* t1 = hc; hc = hn; hn = t1;
        ushort* t2 = hbc; hbc = hbn; hbn = t2;
    }

    // edge MLP (persistent weights)
    k_mlp2<<<MLP_GRID, 512, 0, stream>>>(hbc, qe, ea, W1, b1, bng, bnb, bnm, bnv, W2, b2, W3, b3, out);
}

// Round 18
// 450.954 us; speedup vs baseline: 1.0723x; 1.0054x over previous
//
#include <hip/hip_runtime.h>
#include <math.h>

#define N_NODES 100000
#define N_EDGES 1600000
#define N_QUERY 200000
#define NODE_IN 32
#define EDGE_IN 8
#define H 64
#define LAYERS 3
#define LN_EPS 1e-5f
#define BN_EPS 1e-5f
#define NBLK 391
#define NBUK 391
#define ACHUNK 4096
#define CAPB 6144

typedef __attribute__((ext_vector_type(8))) short short8b;
typedef __attribute__((ext_vector_type(4))) float f32x4;

__device__ __forceinline__ float gelu_f(float x){
    return 0.5f * x * (1.0f + erff(x * 0.70710678118654752440f));
}
__device__ __forceinline__ ushort f2bf(float x){  // RNE f32->bf16
    unsigned u = __float_as_uint(x);
    unsigned r = (u + 0x7FFFu + ((u >> 16) & 1u)) >> 16;
    return (ushort)r;
}
__device__ __forceinline__ float bf2f(ushort x){
    return __uint_as_float(((unsigned)x) << 16);
}

// ---------------- CSR build (bucketed) ----------------
__global__ __launch_bounds__(256) void k_count(const int* __restrict__ ei, int* __restrict__ c){
    int i = blockIdx.x * 256 + threadIdx.x;
    if (i < N_EDGES) atomicAdd(&c[ei[N_EDGES + i]], 1);
}
__global__ __launch_bounds__(256) void k_scanA(const int* __restrict__ cnt, int* __restrict__ bsum){
    int i = blockIdx.x * 256 + threadIdx.x;
    int v = (i < N_NODES) ? cnt[i] : 0;
    #pragma unroll
    for (int off = 32; off; off >>= 1) v += __shfl_xor(v, off, 64);
    __shared__ int ws[4];
    if ((threadIdx.x & 63) == 0) ws[threadIdx.x >> 6] = v;
    __syncthreads();
    if (threadIdx.x == 0) bsum[blockIdx.x] = ws[0] + ws[1] + ws[2] + ws[3];
}
__global__ __launch_bounds__(512) void k_scanB(int* __restrict__ bsum){
    __shared__ int s[512];
    int t = threadIdx.x;
    int v = (t < NBLK) ? bsum[t] : 0;
    s[t] = v; __syncthreads();
    for (int off = 1; off < 512; off <<= 1){
        int u = (t >= off) ? s[t - off] : 0;
        __syncthreads();
        s[t] += u;
        __syncthreads();
    }
    if (t < NBLK) bsum[t] = s[t] - v;
}
__global__ __launch_bounds__(256) void k_scanC(const int* __restrict__ cnt, const int* __restrict__ bsum,
                                               int* __restrict__ rs, int* __restrict__ bcur){
    __shared__ int s[256];
    int t = threadIdx.x;
    int i = blockIdx.x * 256 + t;
    int v = (i < N_NODES) ? cnt[i] : 0;
    s[t] = v; __syncthreads();
    for (int off = 1; off < 256; off <<= 1){
        int u = (t >= off) ? s[t - off] : 0;
        __syncthreads();
        s[t] += u;
        __syncthreads();
    }
    int pref = bsum[blockIdx.x] + s[t] - v;
    if (i < N_NODES) rs[i] = pref;
    if (i == N_NODES - 1) rs[N_NODES] = pref + v;
    if (t == 0) bcur[blockIdx.x] = bsum[blockIdx.x];
}
__global__ __launch_bounds__(1024) void k_bucketA(const int* __restrict__ ei, int* __restrict__ bcur,
                                                  int* __restrict__ bucketed){
    __shared__ int hist[NBUK], pref[NBUK], curl[NBUK], gbase[NBUK];
    __shared__ int scan[512];
    __shared__ int stageP[ACHUNK];
    __shared__ ushort stageB[ACHUNK];
    int tid = threadIdx.x;
    int e0 = blockIdx.x * ACHUNK;
    int cnt = N_EDGES - e0;
    if (cnt > ACHUNK) cnt = ACHUNK;
    for (int b = tid; b < NBUK; b += 1024) hist[b] = 0;
    __syncthreads();
    int myd[4], mys[4];
    #pragma unroll
    for (int i = 0; i < 4; ++i){
        int idx = tid + i * 1024;
        if (idx < cnt){
            int e = e0 + idx;
            mys[i] = ei[e];
            myd[i] = ei[N_EDGES + e];
            atomicAdd(&hist[myd[i] >> 8], 1);
        } else myd[i] = -1;
    }
    __syncthreads();
    int v = (tid < NBUK) ? hist[tid] : 0;
    if (tid < 512) scan[tid] = v;
    __syncthreads();
    for (int off = 1; off < 512; off <<= 1){
        int u = 0;
        if (tid < 512 && tid >= off) u = scan[tid - off];
        __syncthreads();
        if (tid < 512) scan[tid] += u;
        __syncthreads();
    }
    if (tid < NBUK){
        int ex = scan[tid] - v;
        pref[tid] = ex;
        curl[tid] = ex;
        if (v > 0) gbase[tid] = atomicAdd(&bcur[tid], v);
    }
    __syncthreads();
    #pragma unroll
    for (int i = 0; i < 4; ++i){
        if (myd[i] >= 0){
            int b = myd[i] >> 8;
            int p = atomicAdd(&curl[b], 1);
            stageP[p] = (mys[i] << 8) | (myd[i] & 255);
            stageB[p] = (ushort)b;
        }
    }
    __syncthreads();
    for (int p = tid; p < cnt; p += 1024){
        int b = stageB[p];
        bucketed[gbase[b] + (p - pref[b])] = stageP[p];
    }
}
__global__ __launch_bounds__(1024) void k_fillB(const int* __restrict__ rs, int* __restrict__ csr){
    __shared__ int packed[CAPB];
    __shared__ int sorted[CAPB];
    __shared__ int hist[256], cur[256];
    __shared__ int scan[256];
    int tid = threadIdx.x;
    int node0 = blockIdx.x * 256;
    int node1 = node0 + 256; if (node1 > N_NODES) node1 = N_NODES;
    int r0 = rs[node0], r1 = rs[node1];
    int L = r1 - r0;
    if (tid < 256) hist[tid] = 0;
    __syncthreads();
    for (int i = tid; i < L; i += 1024){
        int pk = csr[r0 + i];
        packed[i] = pk;
        atomicAdd(&hist[pk & 255], 1);
    }
    __syncthreads();
    int v = (tid < 256) ? hist[tid] : 0;
    if (tid < 256) scan[tid] = v;
    __syncthreads();
    for (int off = 1; off < 256; off <<= 1){
        int u = 0;
        if (tid < 256 && tid >= off) u = scan[tid - off];
        __syncthreads();
        if (tid < 256) scan[tid] += u;
        __syncthreads();
    }
    if (tid < 256) cur[tid] = scan[tid] - v;
    __syncthreads();
    for (int i = tid; i < L; i += 1024){
        int pk = packed[i];
        int p = atomicAdd(&cur[pk & 255], 1);
        sorted[p] = pk >> 8;
    }
    __syncthreads();
    for (int i = tid; i < L; i += 1024) csr[r0 + i] = sorted[i];
}

// ---------------- node encoder (f32 + flat bf16 mirror) ----------------
__global__ __launch_bounds__(256) void k_enc(const float* __restrict__ x, const float* __restrict__ Wenc,
                                             const float* __restrict__ benc, float* __restrict__ h,
                                             ushort* __restrict__ hbf){
    __shared__ __align__(16) float sW[NODE_IN * H];
    __shared__ float sx[4][NODE_IN];
    int tid = threadIdx.x;
    int lane = tid & 63;
    int w = tid >> 6;
    int n = blockIdx.x * 4 + w;
    for (int i = tid; i < NODE_IN * H; i += 256) sW[i] = Wenc[i];
    if (n < N_NODES && lane < NODE_IN) sx[w][lane] = x[n * NODE_IN + lane];
    __syncthreads();
    if (n < N_NODES){
        float acc = benc[lane];
        #pragma unroll
        for (int k = 0; k < NODE_IN; ++k)
            acc = fmaf(sx[w][k], sW[k * H + lane], acc);
        h[n * H + lane] = acc;
        hbf[n * H + lane] = f2bf(acc);
    }
}

// ------------- MFMA SAGE layer v10: r15 config (NT=32, 512 thr, 4 blk/CU) + persistent grid -------------
// A = [mean | max | h] : [32 rows][192 k] bf16, stride 200
// W = [Wl ; Wr] stacked [192 k][64 f], bf16, transposed [f][k], stride 200
// LDS: sAh 12800 + sW 25600 + sRed 1024 = 39424B -> 4 blocks/CU
#define NT 32
#define SAGE_GRID 1024
#define SAGE_TILES ((N_NODES + NT - 1) / NT)
__global__ __launch_bounds__(512, 8) void k_sage_mfma(const float* __restrict__ h,
    const ushort* __restrict__ hbf,
    const int* __restrict__ rs, const int* __restrict__ csr,
    const float* __restrict__ Wl, const float* __restrict__ bl, const float* __restrict__ Wr,
    const float* __restrict__ lng, const float* __restrict__ lnb,
    float* __restrict__ hout, ushort* __restrict__ hbfout)
{
    __shared__ __align__(16) ushort sAh[NT * 200];
    __shared__ __align__(16) ushort sW[64 * 200];
    __shared__ float2 sRed[8][16];
    const int tid = threadIdx.x;
    const int lane = tid & 63;
    const int w = tid >> 6;
    const int l15 = lane & 15;
    const int kb = lane >> 4;
    const int c4 = l15 * 4;

    // ---- stage W once per (persistent) block ----
    for (int i = tid; i < 128 * 64; i += 512){
        int k = i >> 6, f = i & 63;
        sW[f * 200 + k] = f2bf(Wl[i]);
    }
    for (int i = tid; i < 64 * 64; i += 512){
        int k = (i >> 6) + 128, f = i & 63;
        sW[f * 200 + k] = f2bf(Wr[i]);
    }
    // per-thread epilogue constants (wave w -> row-tile w&1, col-tile w>>1)
    const int rt = w & 1;
    const int c0 = (w >> 1) * 16;
    const int f = c0 + l15;
    const float blf = bl[f], gf = lng[f], bfv = lnb[f];
    const int arow = (rt * 16 + l15) * 200 + kb * 8;
    const int brow = (c0 + l15) * 200 + kb * 8;
    __syncthreads();

    for (int tile = blockIdx.x; tile < SAGE_TILES; tile += SAGE_GRID){
        const int n0 = tile * NT;
        // ---- gather: wave w handles 4 nodes; 4 edges per 8B bf16 load ----
        for (int i = 0; i < 4; ++i){
            int nl = (w << 2) + i;
            int n = n0 + nl;
            float s0 = 0.f, s1 = 0.f, s2 = 0.f, s3 = 0.f;
            float m0 = -INFINITY, m1 = -INFINITY, m2 = -INFINITY, m3 = -INFINITY;
            int dg = 0;
            float4 hv4 = make_float4(0.f, 0.f, 0.f, 0.f);
            if (n < N_NODES){
                int start = rs[n], end = rs[n + 1];
                dg = end - start;
                hv4 = *(const float4*)(h + (size_t)n * H + c4);
                const int* cp = csr + start;
                int nfull = dg >> 2;
                #pragma unroll 4
                for (int j = 0; j < nfull; ++j){
                    int s = cp[j * 4 + kb];
                    const ushort4 u = *(const ushort4*)(hbf + ((size_t)s << 6) + c4);
                    float v0 = bf2f(u.x), v1 = bf2f(u.y), v2 = bf2f(u.z), v3 = bf2f(u.w);
                    s0 += v0; s1 += v1; s2 += v2; s3 += v3;
                    m0 = fmaxf(m0, v0); m1 = fmaxf(m1, v1);
                    m2 = fmaxf(m2, v2); m3 = fmaxf(m3, v3);
                }
                int rem = dg & 3;
                if (rem){
                    int e = nfull * 4 + kb;
                    int s = cp[(kb < rem) ? e : 0];
                    const ushort4 u = *(const ushort4*)(hbf + ((size_t)s << 6) + c4);
                    float v0 = bf2f(u.x), v1 = bf2f(u.y), v2 = bf2f(u.z), v3 = bf2f(u.w);
                    bool val = kb < rem;
                    s0 += val ? v0 : 0.f;  s1 += val ? v1 : 0.f;
                    s2 += val ? v2 : 0.f;  s3 += val ? v3 : 0.f;
                    m0 = fmaxf(m0, val ? v0 : -INFINITY);
                    m1 = fmaxf(m1, val ? v1 : -INFINITY);
                    m2 = fmaxf(m2, val ? v2 : -INFINITY);
                    m3 = fmaxf(m3, val ? v3 : -INFINITY);
                }
            }
            #pragma unroll
            for (int off = 16; off < 64; off <<= 1){
                s0 += __shfl_xor(s0, off, 64); s1 += __shfl_xor(s1, off, 64);
                s2 += __shfl_xor(s2, off, 64); s3 += __shfl_xor(s3, off, 64);
                m0 = fmaxf(m0, __shfl_xor(m0, off, 64)); m1 = fmaxf(m1, __shfl_xor(m1, off, 64));
                m2 = fmaxf(m2, __shfl_xor(m2, off, 64)); m3 = fmaxf(m3, __shfl_xor(m3, off, 64));
            }
            float inv = (dg > 0) ? (1.f / (float)dg) : 0.f;
            float4 val;
            if (kb == 0)      val = make_float4(s0 * inv, s1 * inv, s2 * inv, s3 * inv);
            else if (kb == 1) val = (dg > 0) ? make_float4(m0, m1, m2, m3) : make_float4(0.f,0.f,0.f,0.f);
            else              val = hv4;
            if (kb < 3){
                ushort4 vh = { f2bf(val.x), f2bf(val.y), f2bf(val.z), f2bf(val.w) };
                *(ushort4*)(sAh + nl * 200 + kb * 64 + c4) = vh;
            }
        }
        __syncthreads();

        // ---- MFMA ----
        f32x4 acc = (f32x4){0.f,0.f,0.f,0.f};
        #pragma unroll
        for (int kc = 0; kc < 6; ++kc){
            short8b ah = *(const short8b*)(sAh + arow + kc * 32);
            short8b b  = *(const short8b*)(sW + brow + kc * 32);
            acc = __builtin_amdgcn_mfma_f32_16x16x32_bf16(ah, b, acc, 0, 0, 0);
        }

        #pragma unroll
        for (int r = 0; r < 4; ++r) acc[r] += blf;
        f32x4 s1v, s2v;
        #pragma unroll
        for (int r = 0; r < 4; ++r){ s1v[r] = acc[r]; s2v[r] = acc[r] * acc[r]; }
        #pragma unroll
        for (int r = 0; r < 4; ++r){
            #pragma unroll
            for (int off = 1; off < 16; off <<= 1){
                s1v[r] += __shfl_xor(s1v[r], off, 64);
                s2v[r] += __shfl_xor(s2v[r], off, 64);
            }
        }
        if (l15 == 0){
            #pragma unroll
            for (int r = 0; r < 4; ++r) sRed[w][kb * 4 + r] = make_float2(s1v[r], s2v[r]);
        }
        __syncthreads();
        const int rowb = n0 + rt * 16 + kb * 4;
        #pragma unroll
        for (int r = 0; r < 4; ++r){
            int row = rowb + r;
            if (row < N_NODES){
                float2 p2 = sRed[w ^ 2][kb * 4 + r];
                float2 p4 = sRed[w ^ 4][kb * 4 + r];
                float2 p6 = sRed[w ^ 6][kb * 4 + r];
                float S1 = s1v[r] + p2.x + p4.x + p6.x;
                float S2 = s2v[r] + p2.y + p4.y + p6.y;
                float mu = S1 * (1.f / 64.f);
                float var = S2 * (1.f / 64.f) - mu * mu;
                float rsv = rsqrtf(var + LN_EPS);
                float y = (acc[r] - mu) * rsv * gf + bfv;
                float o = gelu_f(y) + h[(size_t)row * H + f];
                hout[(size_t)row * H + f] = o;
                hbfout[(size_t)row * H + f] = f2bf(o);
            }
        }
        __syncthreads();   // protect sAh/sRed before next tile
    }
}

// ------------- persistent-weight MFMA edge MLP -------------
#define QB2 64
#define MLP_TILES (N_QUERY / QB2)
#define MLP_GRID 512
__global__ __launch_bounds__(512, 2) void k_mlp2(const ushort* __restrict__ hbf,
    const int* __restrict__ qe, const float* __restrict__ ea,
    const float* __restrict__ W1, const float* __restrict__ b1,
    const float* __restrict__ bng, const float* __restrict__ bnb,
    const float* __restrict__ bnm, const float* __restrict__ bnv,
    const float* __restrict__ W2, const float* __restrict__ b2,
    const float* __restrict__ W3, const float* __restrict__ b3,
    float* __restrict__ out)
{
    __shared__ __align__(16) ushort sW1[128 * 136 + 32];
    __shared__ __align__(16) ushort sW2[64 * 136];
    __shared__ __align__(16) ushort sZ[QB2 * 168];
    __shared__ float sRedO[8][16];
    const int tid = threadIdx.x;
    const int lane = tid & 63;
    const int w = tid >> 6;
    const int l15 = lane & 15;
    const int kb = lane >> 4;
    const int rt = w & 3;
    const int whalf = w >> 2;

    for (int i = tid; i < 136 * 128; i += 512){
        int k = i >> 7, j = i & 127;
        sW1[j * 136 + k] = f2bf(W1[i]);
    }
    if (tid < 32) sW1[128 * 136 + tid] = 0;
    for (int i = tid; i < 64 * 128; i += 512){
        int k = i >> 6, f = i & 63;
        sW2[f * 136 + k] = f2bf(W2[i]);
    }
    float scn[4], shn[4];
    #pragma unroll
    for (int n = 0; n < 4; ++n){
        int j = whalf * 64 + n * 16 + l15;
        float sc = bng[j] * rsqrtf(bnv[j] + BN_EPS);
        scn[n] = sc;
        shn[n] = bnb[j] - bnm[j] * sc + b1[j] * sc;
    }
    float b2f[2], w3f[2];
    #pragma unroll
    for (int n = 0; n < 2; ++n){
        int f = whalf * 32 + n * 16 + l15;
        b2f[n] = b2[f]; w3f[n] = W3[f];
    }
    float b3v = b3[0];
    __syncthreads();

    for (int t = blockIdx.x; t < MLP_TILES; t += MLP_GRID){
        int q0 = t * QB2;
        {
            int tq = tid >> 3, part = tid & 7;
            int q = q0 + tq;
            ushort* dst = sZ + tq * 168;
            if (part < 4){
                int sidx = qe[q];
                const ushort* src = hbf + (size_t)sidx * H + part * 16;
                *(short8b*)(dst + part * 16)     = *(const short8b*)(src);
                *(short8b*)(dst + part * 16 + 8) = *(const short8b*)(src + 8);
            } else {
                int tidx = qe[N_QUERY + q];
                const ushort* src = hbf + (size_t)tidx * H + (part - 4) * 16;
                *(short8b*)(dst + 64 + (part - 4) * 16)     = *(const short8b*)(src);
                *(short8b*)(dst + 64 + (part - 4) * 16 + 8) = *(const short8b*)(src + 8);
                ushort4 zz = { 0, 0, 0, 0 };
                *(ushort4*)(dst + 136 + (part - 4) * 8)     = zz;
                *(ushort4*)(dst + 136 + (part - 4) * 8 + 4) = zz;
            }
            if (part == 0){
                const float4* ep = (const float4*)(ea + (size_t)q * 8);
                float4 e0 = ep[0], e1 = ep[1];
                ushort4 o0 = { f2bf(e0.x), f2bf(e0.y), f2bf(e0.z), f2bf(e0.w) };
                ushort4 o1 = { f2bf(e1.x), f2bf(e1.y), f2bf(e1.z), f2bf(e1.w) };
                *(ushort4*)(dst + 128) = o0;
                *(ushort4*)(dst + 132) = o1;
            }
        }
        __syncthreads();

        f32x4 acc[4];
        #pragma unroll
        for (int n = 0; n < 4; ++n) acc[n] = (f32x4){0.f, 0.f, 0.f, 0.f};
        const int arow = (rt * 16 + l15) * 168 + kb * 8;
        #pragma unroll
        for (int kc = 0; kc < 5; ++kc){
            short8b a = *(const short8b*)(sZ + arow + kc * 32);
            #pragma unroll
            for (int n = 0; n < 4; ++n){
                int j = whalf * 64 + n * 16 + l15;
                short8b b = *(const short8b*)(sW1 + j * 136 + kc * 32 + kb * 8);
                acc[n] = __builtin_amdgcn_mfma_f32_16x16x32_bf16(a, b, acc[n], 0, 0, 0);
            }
        }
        __syncthreads();
        #pragma unroll
        for (int n = 0; n < 4; ++n){
            #pragma unroll
            for (int r = 0; r < 4; ++r){
                float v = acc[n][r] * scn[n] + shn[n];
                sZ[(rt * 16 + kb * 4 + r) * 136 + whalf * 64 + n * 16 + l15] = f2bf(gelu_f(v));
            }
        }
        __syncthreads();

        f32x4 acc2[2];
        acc2[0] = (f32x4){0.f,0.f,0.f,0.f};
        acc2[1] = (f32x4){0.f,0.f,0.f,0.f};
        const int arow2 = (rt * 16 + l15) * 136 + kb * 8;
        #pragma unroll
        for (int s = 0; s < 4; ++s){
            short8b a = *(const short8b*)(sZ + arow2 + s * 32);
            #pragma unroll
            for (int n = 0; n < 2; ++n){
                int f = whalf * 32 + n * 16 + l15;
                short8b b = *(const short8b*)(sW2 + f * 136 + s * 32 + kb * 8);
                acc2[n] = __builtin_amdgcn_mfma_f32_16x16x32_bf16(a, b, acc2[n], 0, 0, 0);
            }
        }
        f32x4 pv = (f32x4){0.f,0.f,0.f,0.f};
        #pragma unroll
        for (int n = 0; n < 2; ++n){
            #pragma unroll
            for (int r = 0; r < 4; ++r)
                pv[r] += gelu_f(acc2[n][r] + b2f[n]) * w3f[n];
        }
        #pragma unroll
        for (int r = 0; r < 4; ++r){
            #pragma unroll
            for (int off = 1; off < 16; off <<= 1)
                pv[r] += __shfl_xor(pv[r], off, 64);
        }
        if (l15 == 0){
            #pragma unroll
            for (int r = 0; r < 4; ++r) sRedO[w][kb * 4 + r] = pv[r];
        }
        __syncthreads();
        if (whalf == 0 && l15 == 0){
            #pragma unroll
            for (int r = 0; r < 4; ++r){
                int q = q0 + rt * 16 + kb * 4 + r;
                out[q] = pv[r] + sRedO[w ^ 4][kb * 4 + r] + b3v;
            }
        }
        __syncthreads();
    }
}

extern "C" void kernel_launch(void* const* d_in, const int* in_sizes, int n_in,
                              void* d_out, int out_size, void* d_ws, size_t ws_size,
                              hipStream_t stream) {
    const float* x    = (const float*)d_in[0];
    const int*   ei   = (const int*)d_in[1];
    const float* ea   = (const float*)d_in[2];
    const int*   qe   = (const int*)d_in[3];
    const float* Wenc = (const float*)d_in[4];
    const float* benc = (const float*)d_in[5];
    const float* Wl   = (const float*)d_in[6];
    const float* bl   = (const float*)d_in[7];
    const float* Wr   = (const float*)d_in[8];
    const float* lng  = (const float*)d_in[9];
    const float* lnb  = (const float*)d_in[10];
    const float* W1   = (const float*)d_in[11];
    const float* b1   = (const float*)d_in[12];
    const float* bng  = (const float*)d_in[13];
    const float* bnb  = (const float*)d_in[14];
    const float* bnm  = (const float*)d_in[15];
    const float* bnv  = (const float*)d_in[16];
    const float* W2   = (const float*)d_in[17];
    const float* b2   = (const float*)d_in[18];
    const float* W3   = (const float*)d_in[19];
    const float* b3   = (const float*)d_in[20];
    float* out = (float*)d_out;

    char* ws = (char*)d_ws;
    const size_t NH = (size_t)N_NODES * H;
    float*  hA   = (float*)ws;   ws += NH * 4;
    float*  hB   = (float*)ws;   ws += NH * 4;
    ushort* hbfA = (ushort*)ws;  ws += NH * 2;
    ushort* hbfB = (ushort*)ws;  ws += NH * 2;
    int*    cnt  = (int*)ws;     ws += (size_t)N_NODES * 4;
    int*    rsb  = (int*)ws;     ws += ((size_t)N_NODES + 4) * 4;
    int*    bcur = (int*)ws;     ws += (size_t)NBUK * 4;
    int*    csr  = (int*)ws;     ws += (size_t)N_EDGES * 4;
    int*    bsum = (int*)ws;     ws += 512 * 4;

    // CSR build (bucketed, wave-coalesced writes)
    hipMemsetAsync(cnt, 0, (size_t)N_NODES * 4, stream);
    k_count<<<(N_EDGES + 255) / 256, 256, 0, stream>>>(ei, cnt);
    k_scanA<<<NBLK, 256, 0, stream>>>(cnt, bsum);
    k_scanB<<<1, 512, 0, stream>>>(bsum);
    k_scanC<<<NBLK, 256, 0, stream>>>(cnt, bsum, rsb, bcur);
    k_bucketA<<<(N_EDGES + ACHUNK - 1) / ACHUNK, 1024, 0, stream>>>(ei, bcur, csr);
    k_fillB<<<NBUK, 1024, 0, stream>>>(rsb, csr);

    // encoder
    k_enc<<<(N_NODES + 3) / 4, 256, 0, stream>>>(x, Wenc, benc, hA, hbfA);

    // SAGE layers (MFMA, NT=32, persistent 1024-block grid, 4 blocks/CU)
    float* hc = hA;  float* hn = hB;
    ushort* hbc = hbfA; ushort* hbn = hbfB;
    for (int l = 0; l < LAYERS; ++l){
        k_sage_mfma<<<SAGE_GRID, 512, 0, stream>>>(hc, hbc, rsb, csr,
            Wl + (size_t)l * 2 * H * H, bl + l * H, Wr + (size_t)l * H * H,
            lng + l * H, lnb + l * H, hn, hbn);
        float* t1 = hc; hc = hn; hn = t1;
        ushort* t2 = hbc; hbc = hbn; hbn = t2;
    }

    // edge MLP (persistent weights)
    k_mlp2<<<MLP_GRID, 512, 0, stream>>>(hbc, qe, ea, W1, b1, bng, bnb, bnm, bnv, W2, b2, W3, b3, out);
}

// Round 19
// 429.214 us; speedup vs baseline: 1.1266x; 1.0507x over previous
//
#include <hip/hip_runtime.h>
#include <math.h>

#define N_NODES 100000
#define N_EDGES 1600000
#define N_QUERY 200000
#define NODE_IN 32
#define EDGE_IN 8
#define H 64
#define LAYERS 3
#define LN_EPS 1e-5f
#define BN_EPS 1e-5f
#define NBLK 391
#define NBUK 391
#define ACHUNK 4096
#define CAPB 6144

typedef __attribute__((ext_vector_type(8))) short short8b;
typedef __attribute__((ext_vector_type(4))) float f32x4;

__device__ __forceinline__ float gelu_f(float x){
    return 0.5f * x * (1.0f + erff(x * 0.70710678118654752440f));
}
__device__ __forceinline__ ushort f2bf(float x){  // RNE f32->bf16
    unsigned u = __float_as_uint(x);
    unsigned r = (u + 0x7FFFu + ((u >> 16) & 1u)) >> 16;
    return (ushort)r;
}
__device__ __forceinline__ float bf2f(ushort x){
    return __uint_as_float(((unsigned)x) << 16);
}

// ---------------- CSR build (bucketed) ----------------
__global__ __launch_bounds__(256) void k_count(const int* __restrict__ ei, int* __restrict__ c){
    int i = blockIdx.x * 256 + threadIdx.x;
    if (i < N_EDGES) atomicAdd(&c[ei[N_EDGES + i]], 1);
}
__global__ __launch_bounds__(256) void k_scanA(const int* __restrict__ cnt, int* __restrict__ bsum){
    int i = blockIdx.x * 256 + threadIdx.x;
    int v = (i < N_NODES) ? cnt[i] : 0;
    #pragma unroll
    for (int off = 32; off; off >>= 1) v += __shfl_xor(v, off, 64);
    __shared__ int ws[4];
    if ((threadIdx.x & 63) == 0) ws[threadIdx.x >> 6] = v;
    __syncthreads();
    if (threadIdx.x == 0) bsum[blockIdx.x] = ws[0] + ws[1] + ws[2] + ws[3];
}
__global__ __launch_bounds__(512) void k_scanB(int* __restrict__ bsum){
    __shared__ int s[512];
    int t = threadIdx.x;
    int v = (t < NBLK) ? bsum[t] : 0;
    s[t] = v; __syncthreads();
    for (int off = 1; off < 512; off <<= 1){
        int u = (t >= off) ? s[t - off] : 0;
        __syncthreads();
        s[t] += u;
        __syncthreads();
    }
    if (t < NBLK) bsum[t] = s[t] - v;
}
__global__ __launch_bounds__(256) void k_scanC(const int* __restrict__ cnt, const int* __restrict__ bsum,
                                               int* __restrict__ rs, int* __restrict__ bcur){
    __shared__ int s[256];
    int t = threadIdx.x;
    int i = blockIdx.x * 256 + t;
    int v = (i < N_NODES) ? cnt[i] : 0;
    s[t] = v; __syncthreads();
    for (int off = 1; off < 256; off <<= 1){
        int u = (t >= off) ? s[t - off] : 0;
        __syncthreads();
        s[t] += u;
        __syncthreads();
    }
    int pref = bsum[blockIdx.x] + s[t] - v;
    if (i < N_NODES) rs[i] = pref;
    if (i == N_NODES - 1) rs[N_NODES] = pref + v;
    if (t == 0) bcur[blockIdx.x] = bsum[blockIdx.x];
}
__global__ __launch_bounds__(1024) void k_bucketA(const int* __restrict__ ei, int* __restrict__ bcur,
                                                  int* __restrict__ bucketed){
    __shared__ int hist[NBUK], pref[NBUK], curl[NBUK], gbase[NBUK];
    __shared__ int scan[512];
    __shared__ int stageP[ACHUNK];
    __shared__ ushort stageB[ACHUNK];
    int tid = threadIdx.x;
    int e0 = blockIdx.x * ACHUNK;
    int cnt = N_EDGES - e0;
    if (cnt > ACHUNK) cnt = ACHUNK;
    for (int b = tid; b < NBUK; b += 1024) hist[b] = 0;
    __syncthreads();
    int myd[4], mys[4];
    #pragma unroll
    for (int i = 0; i < 4; ++i){
        int idx = tid + i * 1024;
        if (idx < cnt){
            int e = e0 + idx;
            mys[i] = ei[e];
            myd[i] = ei[N_EDGES + e];
            atomicAdd(&hist[myd[i] >> 8], 1);
        } else myd[i] = -1;
    }
    __syncthreads();
    int v = (tid < NBUK) ? hist[tid] : 0;
    if (tid < 512) scan[tid] = v;
    __syncthreads();
    for (int off = 1; off < 512; off <<= 1){
        int u = 0;
        if (tid < 512 && tid >= off) u = scan[tid - off];
        __syncthreads();
        if (tid < 512) scan[tid] += u;
        __syncthreads();
    }
    if (tid < NBUK){
        int ex = scan[tid] - v;
        pref[tid] = ex;
        curl[tid] = ex;
        if (v > 0) gbase[tid] = atomicAdd(&bcur[tid], v);
    }
    __syncthreads();
    #pragma unroll
    for (int i = 0; i < 4; ++i){
        if (myd[i] >= 0){
            int b = myd[i] >> 8;
            int p = atomicAdd(&curl[b], 1);
            stageP[p] = (mys[i] << 8) | (myd[i] & 255);
            stageB[p] = (ushort)b;
        }
    }
    __syncthreads();
    for (int p = tid; p < cnt; p += 1024){
        int b = stageB[p];
        bucketed[gbase[b] + (p - pref[b])] = stageP[p];
    }
}
__global__ __launch_bounds__(1024) void k_fillB(const int* __restrict__ rs, int* __restrict__ csr){
    __shared__ int packed[CAPB];
    __shared__ int sorted[CAPB];
    __shared__ int hist[256], cur[256];
    __shared__ int scan[256];
    int tid = threadIdx.x;
    int node0 = blockIdx.x * 256;
    int node1 = node0 + 256; if (node1 > N_NODES) node1 = N_NODES;
    int r0 = rs[node0], r1 = rs[node1];
    int L = r1 - r0;
    if (tid < 256) hist[tid] = 0;
    __syncthreads();
    for (int i = tid; i < L; i += 1024){
        int pk = csr[r0 + i];
        packed[i] = pk;
        atomicAdd(&hist[pk & 255], 1);
    }
    __syncthreads();
    int v = (tid < 256) ? hist[tid] : 0;
    if (tid < 256) scan[tid] = v;
    __syncthreads();
    for (int off = 1; off < 256; off <<= 1){
        int u = 0;
        if (tid < 256 && tid >= off) u = scan[tid - off];
        __syncthreads();
        if (tid < 256) scan[tid] += u;
        __syncthreads();
    }
    if (tid < 256) cur[tid] = scan[tid] - v;
    __syncthreads();
    for (int i = tid; i < L; i += 1024){
        int pk = packed[i];
        int p = atomicAdd(&cur[pk & 255], 1);
        sorted[p] = pk >> 8;
    }
    __syncthreads();
    for (int i = tid; i < L; i += 1024) csr[r0 + i] = sorted[i];
}

// ---------------- node encoder (f32 + flat bf16 mirror) ----------------
__global__ __launch_bounds__(256) void k_enc(const float* __restrict__ x, const float* __restrict__ Wenc,
                                             const float* __restrict__ benc, float* __restrict__ h,
                                             ushort* __restrict__ hbf){
    __shared__ __align__(16) float sW[NODE_IN * H];
    __shared__ float sx[4][NODE_IN];
    int tid = threadIdx.x;
    int lane = tid & 63;
    int w = tid >> 6;
    int n = blockIdx.x * 4 + w;
    for (int i = tid; i < NODE_IN * H; i += 256) sW[i] = Wenc[i];
    if (n < N_NODES && lane < NODE_IN) sx[w][lane] = x[n * NODE_IN + lane];
    __syncthreads();
    if (n < N_NODES){
        float acc = benc[lane];
        #pragma unroll
        for (int k = 0; k < NODE_IN; ++k)
            acc = fmaf(sx[w][k], sW[k * H + lane], acc);
        h[n * H + lane] = acc;
        hbf[n * H + lane] = f2bf(acc);
    }
}

// ------------- MFMA SAGE layer (r15 best): single-bf16 A, NT=32, 512 thr, 4 blocks/CU -------------
// A = [mean | max | h] : [32 rows][192 k] bf16, stride 200
// W = [Wl ; Wr] stacked [192 k][64 f], bf16, transposed [f][k], stride 200
// LDS: sAh 12800 + sW 25600 + sRed 1024 = 39424B -> 4 blocks/CU
#define NT 32
__global__ __launch_bounds__(512, 8) void k_sage_mfma(const float* __restrict__ h,
    const ushort* __restrict__ hbf,
    const int* __restrict__ rs, const int* __restrict__ csr,
    const float* __restrict__ Wl, const float* __restrict__ bl, const float* __restrict__ Wr,
    const float* __restrict__ lng, const float* __restrict__ lnb,
    float* __restrict__ hout, ushort* __restrict__ hbfout)
{
    __shared__ __align__(16) ushort sAh[NT * 200];
    __shared__ __align__(16) ushort sW[64 * 200];
    __shared__ float2 sRed[8][16];
    const int tid = threadIdx.x;
    const int lane = tid & 63;
    const int w = tid >> 6;
    const int l15 = lane & 15;
    const int kb = lane >> 4;
    const int c4 = l15 * 4;
    const int n0 = blockIdx.x * NT;

    for (int i = tid; i < 128 * 64; i += 512){
        int k = i >> 6, f = i & 63;
        sW[f * 200 + k] = f2bf(Wl[i]);
    }
    for (int i = tid; i < 64 * 64; i += 512){
        int k = (i >> 6) + 128, f = i & 63;
        sW[f * 200 + k] = f2bf(Wr[i]);
    }

    for (int i = 0; i < 4; ++i){
        int nl = (w << 2) + i;
        int n = n0 + nl;
        float s0 = 0.f, s1 = 0.f, s2 = 0.f, s3 = 0.f;
        float m0 = -INFINITY, m1 = -INFINITY, m2 = -INFINITY, m3 = -INFINITY;
        int dg = 0;
        float4 hv4 = make_float4(0.f, 0.f, 0.f, 0.f);
        if (n < N_NODES){
            int start = rs[n], end = rs[n + 1];
            dg = end - start;
            hv4 = *(const float4*)(h + (size_t)n * H + c4);
            const int* cp = csr + start;
            int nfull = dg >> 2;
            #pragma unroll 4
            for (int j = 0; j < nfull; ++j){
                int s = cp[j * 4 + kb];
                const ushort4 u = *(const ushort4*)(hbf + ((size_t)s << 6) + c4);
                float v0 = bf2f(u.x), v1 = bf2f(u.y), v2 = bf2f(u.z), v3 = bf2f(u.w);
                s0 += v0; s1 += v1; s2 += v2; s3 += v3;
                m0 = fmaxf(m0, v0); m1 = fmaxf(m1, v1);
                m2 = fmaxf(m2, v2); m3 = fmaxf(m3, v3);
            }
            int rem = dg & 3;
            if (rem){
                int e = nfull * 4 + kb;
                int s = cp[(kb < rem) ? e : 0];
                const ushort4 u = *(const ushort4*)(hbf + ((size_t)s << 6) + c4);
                float v0 = bf2f(u.x), v1 = bf2f(u.y), v2 = bf2f(u.z), v3 = bf2f(u.w);
                bool val = kb < rem;
                s0 += val ? v0 : 0.f;  s1 += val ? v1 : 0.f;
                s2 += val ? v2 : 0.f;  s3 += val ? v3 : 0.f;
                m0 = fmaxf(m0, val ? v0 : -INFINITY);
                m1 = fmaxf(m1, val ? v1 : -INFINITY);
                m2 = fmaxf(m2, val ? v2 : -INFINITY);
                m3 = fmaxf(m3, val ? v3 : -INFINITY);
            }
        }
        #pragma unroll
        for (int off = 16; off < 64; off <<= 1){
            s0 += __shfl_xor(s0, off, 64); s1 += __shfl_xor(s1, off, 64);
            s2 += __shfl_xor(s2, off, 64); s3 += __shfl_xor(s3, off, 64);
            m0 = fmaxf(m0, __shfl_xor(m0, off, 64)); m1 = fmaxf(m1, __shfl_xor(m1, off, 64));
            m2 = fmaxf(m2, __shfl_xor(m2, off, 64)); m3 = fmaxf(m3, __shfl_xor(m3, off, 64));
        }
        float inv = (dg > 0) ? (1.f / (float)dg) : 0.f;
        float4 val;
        if (kb == 0)      val = make_float4(s0 * inv, s1 * inv, s2 * inv, s3 * inv);
        else if (kb == 1) val = (dg > 0) ? make_float4(m0, m1, m2, m3) : make_float4(0.f,0.f,0.f,0.f);
        else              val = hv4;
        if (kb < 3){
            ushort4 vh = { f2bf(val.x), f2bf(val.y), f2bf(val.z), f2bf(val.w) };
            *(ushort4*)(sAh + nl * 200 + kb * 64 + c4) = vh;
        }
    }
    __syncthreads();

    // ---- MFMA: wave w -> row-tile (w&1)*16, col-tile (w>>1)*16 ----
    f32x4 acc = (f32x4){0.f,0.f,0.f,0.f};
    const int rt = w & 1;
    const int c0 = (w >> 1) * 16;
    const int arow = (rt * 16 + l15) * 200 + kb * 8;
    const int brow = (c0 + l15) * 200 + kb * 8;
    #pragma unroll
    for (int kc = 0; kc < 6; ++kc){
        short8b ah = *(const short8b*)(sAh + arow + kc * 32);
        short8b b  = *(const short8b*)(sW + brow + kc * 32);
        acc = __builtin_amdgcn_mfma_f32_16x16x32_bf16(ah, b, acc, 0, 0, 0);
    }

    const int f = c0 + l15;
    float blf = bl[f], gf = lng[f], bfv = lnb[f];
    #pragma unroll
    for (int r = 0; r < 4; ++r) acc[r] += blf;
    f32x4 s1v, s2v;
    #pragma unroll
    for (int r = 0; r < 4; ++r){ s1v[r] = acc[r]; s2v[r] = acc[r] * acc[r]; }
    #pragma unroll
    for (int r = 0; r < 4; ++r){
        #pragma unroll
        for (int off = 1; off < 16; off <<= 1){
            s1v[r] += __shfl_xor(s1v[r], off, 64);
            s2v[r] += __shfl_xor(s2v[r], off, 64);
        }
    }
    if (l15 == 0){
        #pragma unroll
        for (int r = 0; r < 4; ++r) sRed[w][kb * 4 + r] = make_float2(s1v[r], s2v[r]);
    }
    __syncthreads();
    const int rowb = n0 + rt * 16 + kb * 4;
    #pragma unroll
    for (int r = 0; r < 4; ++r){
        int row = rowb + r;
        if (row < N_NODES){
            float2 p2 = sRed[w ^ 2][kb * 4 + r];
            float2 p4 = sRed[w ^ 4][kb * 4 + r];
            float2 p6 = sRed[w ^ 6][kb * 4 + r];
            float S1 = s1v[r] + p2.x + p4.x + p6.x;
            float S2 = s2v[r] + p2.y + p4.y + p6.y;
            float mu = S1 * (1.f / 64.f);
            float var = S2 * (1.f / 64.f) - mu * mu;
            float rsv = rsqrtf(var + LN_EPS);
            float y = (acc[r] - mu) * rsv * gf + bfv;
            float o = gelu_f(y) + h[row * H + f];
            hout[row * H + f] = o;
            hbfout[row * H + f] = f2bf(o);
        }
    }
}

// ------------- persistent-weight MFMA edge MLP -------------
#define QB2 64
#define MLP_TILES (N_QUERY / QB2)
#define MLP_GRID 512
__global__ __launch_bounds__(512, 2) void k_mlp2(const ushort* __restrict__ hbf,
    const int* __restrict__ qe, const float* __restrict__ ea,
    const float* __restrict__ W1, const float* __restrict__ b1,
    const float* __restrict__ bng, const float* __restrict__ bnb,
    const float* __restrict__ bnm, const float* __restrict__ bnv,
    const float* __restrict__ W2, const float* __restrict__ b2,
    const float* __restrict__ W3, const float* __restrict__ b3,
    float* __restrict__ out)
{
    __shared__ __align__(16) ushort sW1[128 * 136 + 32];
    __shared__ __align__(16) ushort sW2[64 * 136];
    __shared__ __align__(16) ushort sZ[QB2 * 168];
    __shared__ float sRedO[8][16];
    const int tid = threadIdx.x;
    const int lane = tid & 63;
    const int w = tid >> 6;
    const int l15 = lane & 15;
    const int kb = lane >> 4;
    const int rt = w & 3;
    const int whalf = w >> 2;

    for (int i = tid; i < 136 * 128; i += 512){
        int k = i >> 7, j = i & 127;
        sW1[j * 136 + k] = f2bf(W1[i]);
    }
    if (tid < 32) sW1[128 * 136 + tid] = 0;
    for (int i = tid; i < 64 * 128; i += 512){
        int k = i >> 6, f = i & 63;
        sW2[f * 136 + k] = f2bf(W2[i]);
    }
    float scn[4], shn[4];
    #pragma unroll
    for (int n = 0; n < 4; ++n){
        int j = whalf * 64 + n * 16 + l15;
        float sc = bng[j] * rsqrtf(bnv[j] + BN_EPS);
        scn[n] = sc;
        shn[n] = bnb[j] - bnm[j] * sc + b1[j] * sc;
    }
    float b2f[2], w3f[2];
    #pragma unroll
    for (int n = 0; n < 2; ++n){
        int f = whalf * 32 + n * 16 + l15;
        b2f[n] = b2[f]; w3f[n] = W3[f];
    }
    float b3v = b3[0];
    __syncthreads();

    for (int t = blockIdx.x; t < MLP_TILES; t += MLP_GRID){
        int q0 = t * QB2;
        {
            int tq = tid >> 3, part = tid & 7;
            int q = q0 + tq;
            ushort* dst = sZ + tq * 168;
            if (part < 4){
                int sidx = qe[q];
                const ushort* src = hbf + (size_t)sidx * H + part * 16;
                *(short8b*)(dst + part * 16)     = *(const short8b*)(src);
                *(short8b*)(dst + part * 16 + 8) = *(const short8b*)(src + 8);
            } else {
                int tidx = qe[N_QUERY + q];
                const ushort* src = hbf + (size_t)tidx * H + (part - 4) * 16;
                *(short8b*)(dst + 64 + (part - 4) * 16)     = *(const short8b*)(src);
                *(short8b*)(dst + 64 + (part - 4) * 16 + 8) = *(const short8b*)(src + 8);
                ushort4 zz = { 0, 0, 0, 0 };
                *(ushort4*)(dst + 136 + (part - 4) * 8)     = zz;
                *(ushort4*)(dst + 136 + (part - 4) * 8 + 4) = zz;
            }
            if (part == 0){
                const float4* ep = (const float4*)(ea + (size_t)q * 8);
                float4 e0 = ep[0], e1 = ep[1];
                ushort4 o0 = { f2bf(e0.x), f2bf(e0.y), f2bf(e0.z), f2bf(e0.w) };
                ushort4 o1 = { f2bf(e1.x), f2bf(e1.y), f2bf(e1.z), f2bf(e1.w) };
                *(ushort4*)(dst + 128) = o0;
                *(ushort4*)(dst + 132) = o1;
            }
        }
        __syncthreads();

        f32x4 acc[4];
        #pragma unroll
        for (int n = 0; n < 4; ++n) acc[n] = (f32x4){0.f, 0.f, 0.f, 0.f};
        const int arow = (rt * 16 + l15) * 168 + kb * 8;
        #pragma unroll
        for (int kc = 0; kc < 5; ++kc){
            short8b a = *(const short8b*)(sZ + arow + kc * 32);
            #pragma unroll
            for (int n = 0; n < 4; ++n){
                int j = whalf * 64 + n * 16 + l15;
                short8b b = *(const short8b*)(sW1 + j * 136 + kc * 32 + kb * 8);
                acc[n] = __builtin_amdgcn_mfma_f32_16x16x32_bf16(a, b, acc[n], 0, 0, 0);
            }
        }
        __syncthreads();
        #pragma unroll
        for (int n = 0; n < 4; ++n){
            #pragma unroll
            for (int r = 0; r < 4; ++r){
                float v = acc[n][r] * scn[n] + shn[n];
                sZ[(rt * 16 + kb * 4 + r) * 136 + whalf * 64 + n * 16 + l15] = f2bf(gelu_f(v));
            }
        }
        __syncthreads();

        f32x4 acc2[2];
        acc2[0] = (f32x4){0.f,0.f,0.f,0.f};
        acc2[1] = (f32x4){0.f,0.f,0.f,0.f};
        const int arow2 = (rt * 16 + l15) * 136 + kb * 8;
        #pragma unroll
        for (int s = 0; s < 4; ++s){
            short8b a = *(const short8b*)(sZ + arow2 + s * 32);
            #pragma unroll
            for (int n = 0; n < 2; ++n){
                int f = whalf * 32 + n * 16 + l15;
                short8b b = *(const short8b*)(sW2 + f * 136 + s * 32 + kb * 8);
                acc2[n] = __builtin_amdgcn_mfma_f32_16x16x32_bf16(a, b, acc2[n], 0, 0, 0);
            }
        }
        f32x4 pv = (f32x4){0.f,0.f,0.f,0.f};
        #pragma unroll
        for (int n = 0; n < 2; ++n){
            #pragma unroll
            for (int r = 0; r < 4; ++r)
                pv[r] += gelu_f(acc2[n][r] + b2f[n]) * w3f[n];
        }
        #pragma unroll
        for (int r = 0; r < 4; ++r){
            #pragma unroll
            for (int off = 1; off < 16; off <<= 1)
                pv[r] += __shfl_xor(pv[r], off, 64);
        }
        if (l15 == 0){
            #pragma unroll
            for (int r = 0; r < 4; ++r) sRedO[w][kb * 4 + r] = pv[r];
        }
        __syncthreads();
        if (whalf == 0 && l15 == 0){
            #pragma unroll
            for (int r = 0; r < 4; ++r){
                int q = q0 + rt * 16 + kb * 4 + r;
                out[q] = pv[r] + sRedO[w ^ 4][kb * 4 + r] + b3v;
            }
        }
        __syncthreads();
    }
}

extern "C" void kernel_launch(void* const* d_in, const int* in_sizes, int n_in,
                              void* d_out, int out_size, void* d_ws, size_t ws_size,
                              hipStream_t stream) {
    const float* x    = (const float*)d_in[0];
    const int*   ei   = (const int*)d_in[1];
    const float* ea   = (const float*)d_in[2];
    const int*   qe   = (const int*)d_in[3];
    const float* Wenc = (const float*)d_in[4];
    const float* benc = (const float*)d_in[5];
    const float* Wl   = (const float*)d_in[6];
    const float* bl   = (const float*)d_in[7];
    const float* Wr   = (const float*)d_in[8];
    const float* lng  = (const float*)d_in[9];
    const float* lnb  = (const float*)d_in[10];
    const float* W1   = (const float*)d_in[11];
    const float* b1   = (const float*)d_in[12];
    const float* bng  = (const float*)d_in[13];
    const float* bnb  = (const float*)d_in[14];
    const float* bnm  = (const float*)d_in[15];
    const float* bnv  = (const float*)d_in[16];
    const float* W2   = (const float*)d_in[17];
    const float* b2   = (const float*)d_in[18];
    const float* W3   = (const float*)d_in[19];
    const float* b3   = (const float*)d_in[20];
    float* out = (float*)d_out;

    char* ws = (char*)d_ws;
    const size_t NH = (size_t)N_NODES * H;
    float*  hA   = (float*)ws;   ws += NH * 4;
    float*  hB   = (float*)ws;   ws += NH * 4;
    ushort* hbfA = (ushort*)ws;  ws += NH * 2;
    ushort* hbfB = (ushort*)ws;  ws += NH * 2;
    int*    cnt  = (int*)ws;     ws += (size_t)N_NODES * 4;
    int*    rsb  = (int*)ws;     ws += ((size_t)N_NODES + 4) * 4;
    int*    bcur = (int*)ws;     ws += (size_t)NBUK * 4;
    int*    csr  = (int*)ws;     ws += (size_t)N_EDGES * 4;
    int*    bsum = (int*)ws;     ws += 512 * 4;

    // CSR build (bucketed, wave-coalesced writes)
    hipMemsetAsync(cnt, 0, (size_t)N_NODES * 4, stream);
    k_count<<<(N_EDGES + 255) / 256, 256, 0, stream>>>(ei, cnt);
    k_scanA<<<NBLK, 256, 0, stream>>>(cnt, bsum);
    k_scanB<<<1, 512, 0, stream>>>(bsum);
    k_scanC<<<NBLK, 256, 0, stream>>>(cnt, bsum, rsb, bcur);
    k_bucketA<<<(N_EDGES + ACHUNK - 1) / ACHUNK, 1024, 0, stream>>>(ei, bcur, csr);
    k_fillB<<<NBUK, 1024, 0, stream>>>(rsb, csr);

    // encoder
    k_enc<<<(N_NODES + 3) / 4, 256, 0, stream>>>(x, Wenc, benc, hA, hbfA);

    // SAGE layers (MFMA, NT=32, 4 blocks/CU)
    int nbn = (N_NODES + NT - 1) / NT;
    float* hc = hA;  float* hn = hB;
    ushort* hbc = hbfA; ushort* hbn = hbfB;
    for (int l = 0; l < LAYERS; ++l){
        k_sage_mfma<<<nbn, 512, 0, stream>>>(hc, hbc, rsb, csr,
            Wl + (size_t)l * 2 * H * H, bl + l * H, Wr + (size_t)l * H * H,
            lng + l * H, lnb + l * H, hn, hbn);
        float* t1 = hc; hc = hn; hn = t1;
        ushort* t2 = hbc; hbc = hbn; hbn = t2;
    }

    // edge MLP (persistent weights)
    k_mlp2<<<MLP_GRID, 512, 0, stream>>>(hbc, qe, ea, W1, b1, bng, bnb, bnm, bnv, W2, b2, W3, b3, out);
}